// Round 1
// 3023.735 us; speedup vs baseline: 1.1051x; 1.1051x over previous
//
#include <hip/hip_runtime.h>
#include <hip/hip_bf16.h>
#include <stdint.h>

#define B_    64
#define LC_   512
#define V_    8192
#define H_    1024
#define PREF_ 16
#define S_    545
#define SP_   560          // padded src rows (545 -> 560 = 35*16)
#define KA_   9216         // Abuf row length: 8192 (y) + 1024 (asrc)
#define NEGV  (-1e9f)
#define INV32 0.03125f     // H^-0.5

typedef __attribute__((ext_vector_type(8))) short s8v;   // 8 bf16 MFMA frag
typedef __attribute__((ext_vector_type(4))) float f4a;   // MFMA C/D frag

__device__ __forceinline__ short f2bf(float f){
  uint32_t u = __float_as_uint(f);
  uint32_t r = (u + 0x7fffu + ((u >> 16) & 1u)) >> 16;
  return (short)(r & 0xffffu);
}
__device__ __forceinline__ float bf2f(short s){
  return __uint_as_float(((uint32_t)(uint16_t)s) << 16);
}

// ---------------- threefry2x32 (exact JAX semantics) ----------------
__device__ __forceinline__ uint32_t rotl32(uint32_t x, uint32_t d){ return (x<<d)|(x>>(32u-d)); }
__device__ __forceinline__ void tf2x32(uint32_t k0, uint32_t k1, uint32_t& x0, uint32_t& x1){
  uint32_t ks0=k0, ks1=k1, ks2=k0^k1^0x1BD11BDAu;
  x0+=ks0; x1+=ks1;
  x0+=x1; x1=rotl32(x1,13); x1^=x0;
  x0+=x1; x1=rotl32(x1,15); x1^=x0;
  x0+=x1; x1=rotl32(x1,26); x1^=x0;
  x0+=x1; x1=rotl32(x1, 6); x1^=x0;
  x0+=ks1; x1+=ks2+1u;
  x0+=x1; x1=rotl32(x1,17); x1^=x0;
  x0+=x1; x1=rotl32(x1,29); x1^=x0;
  x0+=x1; x1=rotl32(x1,16); x1^=x0;
  x0+=x1; x1=rotl32(x1,24); x1^=x0;
  x0+=ks2; x1+=ks0+2u;
  x0+=x1; x1=rotl32(x1,13); x1^=x0;
  x0+=x1; x1=rotl32(x1,15); x1^=x0;
  x0+=x1; x1=rotl32(x1,26); x1^=x0;
  x0+=x1; x1=rotl32(x1, 6); x1^=x0;
  x0+=ks0; x1+=ks1+3u;
  x0+=x1; x1=rotl32(x1,17); x1^=x0;
  x0+=x1; x1=rotl32(x1,29); x1^=x0;
  x0+=x1; x1=rotl32(x1,16); x1^=x0;
  x0+=x1; x1=rotl32(x1,24); x1^=x0;
  x0+=ks1; x1+=ks2+4u;
  x0+=x1; x1=rotl32(x1,13); x1^=x0;
  x0+=x1; x1=rotl32(x1,15); x1^=x0;
  x0+=x1; x1=rotl32(x1,26); x1^=x0;
  x0+=x1; x1=rotl32(x1, 6); x1^=x0;
  x0+=ks2; x1+=ks0+5u;
}

// ---------------- casts ----------------
__global__ __launch_bounds__(256) void cast_bf(const float* __restrict__ in, short* __restrict__ out){
  size_t idx = ((size_t)blockIdx.x*256 + threadIdx.x)*4;
  float4 v = *(const float4*)(in+idx);
  short4 s; s.x=f2bf(v.x); s.y=f2bf(v.y); s.z=f2bf(v.z); s.w=f2bf(v.w);
  *(short4*)(out+idx) = s;
}
// fp32 [K][N] -> k-packeted bf16: off(k,n) = ((k>>3)*N + n)*8 + (k&7)
__global__ __launch_bounds__(256) void cast_pack(const float* __restrict__ in, short* __restrict__ out, int N){
  int gid = blockIdx.x*256 + threadIdx.x;
  int k = gid / (N>>2);
  int n = (gid % (N>>2))*4;
  float4 v = *(const float4*)(in + (size_t)k*N + n);
  size_t base = ((size_t)(k>>3)*N + n)*8 + (k&7);
  out[base] = f2bf(v.x); out[base+8] = f2bf(v.y); out[base+16] = f2bf(v.z); out[base+24] = f2bf(v.w);
}

// ---------------- bf16-in GEMM: A row-major bf16 (direct-global frags), B k-packeted bf16 ----------------
template<int BM, bool ATOMIC, bool BIAS>
__global__ __launch_bounds__(256) void bgemm(
    const short* __restrict__ A, int lda,
    const short* __restrict__ Bp, int ldn,
    float* __restrict__ C, int ldc,
    int kchunk, const float* __restrict__ bias)
{
  constexpr int BN = 128, BK = 64;
  __shared__ short Bl[BK*BN];
  const int t = threadIdx.x;
  const int w = t >> 6, lane = t & 63;
  const int quad = lane >> 4, l16 = lane & 15;
  const int col0 = blockIdx.x * BN;
  const int row0 = (BM==128) ? blockIdx.y * BM : 0;
  const int k0 = blockIdx.z * kchunk, kend = k0 + kchunk;
  constexpr int MT = 2;
  constexpr int NT = (BM==128) ? 8 : 4;
  const int mbase = (BM==128) ? w*32 : (w&1)*32;
  const int nbase = (BM==128) ? 0 : (w>>1)*64;
  f4a acc[MT][NT];
  #pragma unroll
  for (int mt=0; mt<MT; mt++)
    #pragma unroll
    for (int nt=0; nt<NT; nt++)
      acc[mt][nt] = (f4a){0.f,0.f,0.f,0.f};

  for (int kb = k0; kb < kend; kb += BK){
    #pragma unroll
    for (int i=0;i<4;i++){                      // stage B tile: 1024 short8
      int idx = t + i*256;
      int p = idx >> 7, n = idx & 127;
      ((s8v*)Bl)[idx] = *(const s8v*)(Bp + (((size_t)((kb>>3)+p))*ldn + col0 + n)*8);
    }
    __syncthreads();
    #pragma unroll
    for (int ks=0; ks<BK; ks+=32){
      const int kk = kb + ks + quad*8;
      const int kl = ks + quad*8;
      s8v af[MT], bfr[NT];
      #pragma unroll
      for (int mt=0; mt<MT; mt++)
        af[mt] = *(const s8v*)(A + (size_t)(row0+mbase+mt*16+l16)*lda + kk);
      #pragma unroll
      for (int nt=0; nt<NT; nt++)
        bfr[nt] = *(const s8v*)&Bl[((kl>>3)*BN + nbase + nt*16 + l16)*8];
      #pragma unroll
      for (int mt=0; mt<MT; mt++)
        #pragma unroll
        for (int nt=0; nt<NT; nt++)
          acc[mt][nt] = __builtin_amdgcn_mfma_f32_16x16x32_bf16(af[mt], bfr[nt], acc[mt][nt], 0, 0, 0);
    }
    __syncthreads();
  }
  #pragma unroll
  for (int mt=0; mt<MT; mt++){
    #pragma unroll
    for (int nt=0; nt<NT; nt++){
      #pragma unroll
      for (int r=0; r<4; r++){
        int row = row0 + mbase + mt*16 + quad*4 + r;
        int cc  = col0 + nbase + nt*16 + l16;
        float v = acc[mt][nt][r];
        if (BIAS){ if (!ATOMIC || blockIdx.z==0) v += bias[cc]; }
        size_t idx = (size_t)row*ldc + cc;
        if (ATOMIC) atomicAdd(&C[idx], v);
        else        C[idx] = v;
      }
    }
  }
}

// ---------------- fp32-in GEMM (setup only), BM=128; PACK: bf16 k-packeted output ----------------
template<bool TRANSB, bool PACK>
__global__ __launch_bounds__(256) void mgemm(
    const float* __restrict__ A, int lda,
    const float* __restrict__ Bm, int ldb,
    float* __restrict__ C, int ldc, int K)
{
  constexpr int BM = 128, BN = 128, BK = 64;
  __shared__ short Ap[BK*BM];
  __shared__ short Bp[BK*BN];
  const int t = threadIdx.x;
  const int w = t >> 6, lane = t & 63;
  const int quad = lane >> 4, l16 = lane & 15;
  const int col0 = blockIdx.x * BN;
  const int row0 = blockIdx.y * BM;
  constexpr int MT = 2, NT = 8;
  const int mbase = w*32, nbase = 0;
  f4a acc[MT][NT];
  #pragma unroll
  for (int mt=0; mt<MT; mt++)
    #pragma unroll
    for (int nt=0; nt<NT; nt++)
      acc[mt][nt] = (f4a){0.f,0.f,0.f,0.f};

  for (int kb = 0; kb < K; kb += BK){
    #pragma unroll
    for (int i = 0; i < 8; ++i){
      int idx = t + i*256;
      int m = idx >> 4, kq = (idx & 15) * 4;
      float4 a = *(const float4*)(A + (size_t)(row0+m)*lda + kb + kq);
      short4 s4; s4.x=f2bf(a.x); s4.y=f2bf(a.y); s4.z=f2bf(a.z); s4.w=f2bf(a.w);
      *(short4*)&Ap[((kq>>3)*BM + m)*8 + (kq&7)] = s4;
    }
    if (TRANSB){
      #pragma unroll
      for (int i = 0; i < 8; ++i){
        int idx = t + i*256;
        int n = idx >> 4, kq = (idx & 15) * 4;
        float4 bv = *(const float4*)(Bm + (size_t)(col0+n)*ldb + kb + kq);
        short4 s4; s4.x=f2bf(bv.x); s4.y=f2bf(bv.y); s4.z=f2bf(bv.z); s4.w=f2bf(bv.w);
        *(short4*)&Bp[((kq>>3)*BN + n)*8 + (kq&7)] = s4;
      }
    } else {
      #pragma unroll
      for (int c = 0; c < 8; ++c){
        int idx = t + c*256;
        int n = idx & 127, kq = (idx >> 7) * 4;
        const float* bp0 = Bm + (size_t)(kb+kq)*ldb + col0 + n;
        float b0 = bp0[0], b1 = bp0[ldb], b2 = bp0[2*(size_t)ldb], b3 = bp0[3*(size_t)ldb];
        short4 s4; s4.x=f2bf(b0); s4.y=f2bf(b1); s4.z=f2bf(b2); s4.w=f2bf(b3);
        *(short4*)&Bp[((kq>>3)*BN + n)*8 + (kq&7)] = s4;
      }
    }
    __syncthreads();
    #pragma unroll
    for (int ks = 0; ks < BK; ks += 32){
      const int kk = ks + quad*8;
      s8v af[MT], bfr[NT];
      #pragma unroll
      for (int mt=0; mt<MT; mt++)
        af[mt] = *(const s8v*)&Ap[((kk>>3)*BM + mbase + mt*16 + l16)*8];
      #pragma unroll
      for (int nt=0; nt<NT; nt++)
        bfr[nt] = *(const s8v*)&Bp[((kk>>3)*BN + nbase + nt*16 + l16)*8];
      #pragma unroll
      for (int mt=0; mt<MT; mt++)
        #pragma unroll
        for (int nt=0; nt<NT; nt++)
          acc[mt][nt] = __builtin_amdgcn_mfma_f32_16x16x32_bf16(af[mt], bfr[nt], acc[mt][nt], 0, 0, 0);
    }
    __syncthreads();
  }
  #pragma unroll
  for (int mt=0; mt<MT; mt++){
    #pragma unroll
    for (int nt=0; nt<NT; nt++){
      #pragma unroll
      for (int r=0; r<4; r++){
        int row = row0 + mbase + mt*16 + quad*4 + r;
        int cc  = col0 + nbase + nt*16 + l16;
        float v = acc[mt][nt][r];
        if (PACK){
          size_t off = (((size_t)(row>>3))*ldc + cc)*8 + (row&7);
          ((short*)C)[off] = f2bf(v);
        } else {
          C[(size_t)row*ldc + cc] = v;
        }
      }
    }
  }
}

// ---------------- src_hidden materialization (bf16) + mask ----------------
// v2: fully coalesced — block handles 2 rows, 128 threads/row, each thread
// reads 32B contiguous and writes one 16B short8 contiguous. Masked ctx rows
// and padding rows are NOT written (every consumer is guarded by smask /
// p != 0), only smask is written for them.
__global__ __launch_bounds__(256) void src_build(
    const float* __restrict__ E_ctx, const int* __restrict__ context, const int* __restrict__ ctx_len,
    const float* __restrict__ pvh, const float* __restrict__ pv_mask,
    const float* __restrict__ tp_hidden, const int* __restrict__ tp_len,
    const float* __restrict__ ar_hidden, const int* __restrict__ ar_len,
    short* __restrict__ src, float* __restrict__ smask)
{
  const int b = blockIdx.x, t = threadIdx.x;
  const int j = blockIdx.y*2 + (t >> 7);        // grid.y = 280 -> j in 0..559
  const int c = (t & 127) * 8;
  const float* srcp = nullptr;
  float msk = 0.f;
  if (j < 512){
    bool on = j < ctx_len[b];
    msk = on ? 1.f : 0.f;
    if (on) srcp = E_ctx + (size_t)context[b*LC_ + j]*H_;   // ref zeroes masked ctx rows (never read)
  } else if (j < 528){
    srcp = pvh + (size_t)(b*16 + j-512)*H_;
    msk = pv_mask[b*16 + j-512];
  } else if (j < 544){
    srcp = tp_hidden + (size_t)(b*16 + j-528)*H_;
    msk = ((j-528) < tp_len[b]) ? 1.f : 0.f;
  } else if (j == 544){
    srcp = ar_hidden + (size_t)b*H_;
    msk = (ar_len[b] > 0) ? 1.f : 0.f;
  }
  if (srcp){
    float4 v0 = *(const float4*)(srcp + c);
    float4 v1 = *(const float4*)(srcp + c + 4);
    s8v s;
    s[0]=f2bf(v0.x); s[1]=f2bf(v0.y); s[2]=f2bf(v0.z); s[3]=f2bf(v0.w);
    s[4]=f2bf(v1.x); s[5]=f2bf(v1.y); s[6]=f2bf(v1.z); s[7]=f2bf(v1.w);
    *(s8v*)(src + (size_t)(b*SP_ + j)*H_ + c) = s;
  }
  if ((t & 127) == 0) smask[b*SP_ + j] = msk;
}

__global__ __launch_bounds__(256) void abuf_init(short* __restrict__ Abuf){
  int v = blockIdx.x*256 + threadIdx.x;  // grid (36, 64)
  int b = blockIdx.y;
  Abuf[(size_t)b*KA_ + v] = (v == 2) ? (short)0x3F80 : (short)0;
}

// ---------------- attention: flash chunk pass over bf16 src ----------------
__global__ __launch_bounds__(256) void attn_pass(
    const float* __restrict__ qk, const short* __restrict__ src, const float* __restrict__ smask,
    float* __restrict__ part_o, float* __restrict__ part_ml)
{
  const int b = blockIdx.x, c = blockIdx.y, t = threadIdx.x;
  const int w = t>>6, lane = t&63;
  __shared__ float sv[70], pr[70], red[4];
  float qreg[16];
  {
    const float4* q4 = (const float4*)(qk + (size_t)b*H_ + lane*16);
    #pragma unroll
    for (int i=0;i<4;i++){ float4 v = q4[i]; qreg[4*i]=v.x; qreg[4*i+1]=v.y; qreg[4*i+2]=v.z; qreg[4*i+3]=v.w; }
  }
  const int j0 = c*70;
  for (int r = w; r < 70; r += 4){
    float msk = smask[b*SP_ + j0 + r];
    float s = -3.4e38f;
    if (msk != 0.f){
      const s8v* rp = (const s8v*)(src + (size_t)(b*SP_ + j0 + r)*H_);
      s8v v0 = rp[lane*2], v1 = rp[lane*2+1];
      float acc = 0.f;
      #pragma unroll
      for (int i=0;i<8;i++) acc += bf2f(v0[i])*qreg[i];
      #pragma unroll
      for (int i=0;i<8;i++) acc += bf2f(v1[i])*qreg[8+i];
      #pragma unroll
      for (int off=32; off; off>>=1) acc += __shfl_down(acc, off, 64);
      s = acc * INV32;
    }
    if (lane == 0) sv[r] = s;
  }
  __syncthreads();
  float lm = (t < 70) ? sv[t] : -3.4e38f;
  #pragma unroll
  for (int off=32; off; off>>=1) lm = fmaxf(lm, __shfl_down(lm, off, 64));
  if (lane==0) red[w] = lm;
  __syncthreads();
  const float m = fmaxf(fmaxf(red[0],red[1]), fmaxf(red[2],red[3]));
  __syncthreads();
  if (t < 70) pr[t] = (sv[t] > -1e37f) ? expf(sv[t]-m) : 0.f;
  __syncthreads();
  float ls = (t < 70) ? pr[t] : 0.f;
  #pragma unroll
  for (int off=32; off; off>>=1) ls += __shfl_down(ls, off, 64);
  if (lane==0) red[w] = ls;
  __syncthreads();
  const float lsum = red[0]+red[1]+red[2]+red[3];
  float4 o = {0.f,0.f,0.f,0.f};
  const short* base = src + (size_t)(b*SP_ + j0)*H_ + t*4;
  for (int r=0;r<70;r++){
    float p_ = pr[r];
    if (p_ != 0.f){
      short4 s4 = *(const short4*)(base + (size_t)r*H_);
      o.x += p_*bf2f(s4.x); o.y += p_*bf2f(s4.y); o.z += p_*bf2f(s4.z); o.w += p_*bf2f(s4.w);
    }
  }
  ((float4*)(part_o + (size_t)(b*8+c)*H_))[t] = o;
  if (t==0){ part_ml[(b*8+c)*2] = m; part_ml[(b*8+c)*2+1] = lsum; }
}

// combine chunks -> asrc, written as bf16 into Abuf cols [8192..9215]
__global__ __launch_bounds__(256) void attn_combine(
    const float* __restrict__ part_o, const float* __restrict__ part_ml,
    short* __restrict__ Abuf)
{
  const int b = blockIdx.x, t = threadIdx.x;
  __shared__ float sm[8], sl[8];
  if (t < 8){ sm[t] = part_ml[(b*8+t)*2]; sl[t] = part_ml[(b*8+t)*2+1]; }
  __syncthreads();
  float M = -3.4e38f;
  #pragma unroll
  for (int i=0;i<8;i++) M = fmaxf(M, sm[i]);
  float wgt[8]; float Z = 0.f;
  #pragma unroll
  for (int i=0;i<8;i++){ wgt[i] = expf(sm[i]-M); Z += wgt[i]*sl[i]; }
  float4 o = {0.f,0.f,0.f,0.f};
  #pragma unroll
  for (int i=0;i<8;i++){
    float4 p = ((const float4*)(part_o + (size_t)(b*8+i)*H_))[t];
    o.x += wgt[i]*p.x; o.y += wgt[i]*p.y; o.z += wgt[i]*p.z; o.w += wgt[i]*p.w;
  }
  float inv = 1.f / Z;
  short4 s4; s4.x=f2bf(o.x*inv); s4.y=f2bf(o.y*inv); s4.z=f2bf(o.z*inv); s4.w=f2bf(o.w*inv);
  *(short4*)(Abuf + (size_t)b*KA_ + 8192 + t*4) = s4;
}

// dtan = bf16(tanh(decr))
__global__ __launch_bounds__(256) void tanhcast(const float* __restrict__ decr, short* __restrict__ dtan){
  int idx = blockIdx.x*256 + threadIdx.x;   // grid 64 -> 16384 float4
  float4 v = ((const float4*)decr)[idx];
  short4 s; s.x=f2bf(tanhf(v.x)); s.y=f2bf(tanhf(v.y)); s.z=f2bf(tanhf(v.z)); s.w=f2bf(tanhf(v.w));
  ((short4*)dtan)[idx] = s;
}

// ---------------- copy logits over bf16 src ----------------
__global__ __launch_bounds__(256) void copy_score(
    const short* __restrict__ dtan, const short* __restrict__ src, const float* __restrict__ smask,
    float* __restrict__ cl)
{
  const int b = blockIdx.x, c = blockIdx.y, t = threadIdx.x;
  const int w = t>>6, lane = t&63;
  float qd[16];
  {
    const s8v* d8 = (const s8v*)(dtan + (size_t)b*H_ + lane*16);
    s8v d0 = d8[0], d1 = d8[1];
    #pragma unroll
    for (int i=0;i<8;i++){ qd[i] = bf2f(d0[i]); qd[8+i] = bf2f(d1[i]); }
  }
  for (int r = w; r < 68; r += 4){
    int j = c*68 + r;
    float msk = smask[b*SP_ + j];
    float s;
    if (msk != 0.f){
      const s8v* rp = (const s8v*)(src + (size_t)(b*SP_ + j)*H_);
      s8v v0 = rp[lane*2], v1 = rp[lane*2+1];
      float acc = 0.f;
      #pragma unroll
      for (int i=0;i<8;i++) acc += bf2f(v0[i])*qd[i];
      #pragma unroll
      for (int i=0;i<8;i++) acc += bf2f(v1[i])*qd[8+i];
      #pragma unroll
      for (int off=32; off; off>>=1) acc += __shfl_down(acc, off, 64);
      s = acc * INV32;
    } else s = NEGV * INV32;
    if (lane == 0) cl[b*544 + j] = s;
  }
}

// ---------------- fused: softmax stats + p build + scatter + gumbel sample ----------------
// v2: 1024 threads (16 waves) — 4x the wave parallelism for the threefry/log
// sampling and the 32 MB/step pv_m stream; RNG depends only on absolute
// element index so the remap is bit-exact vs the 256-thread version.
__global__ __launch_bounds__(1024) void fuse_out(
    const float* __restrict__ gen, const float* __restrict__ cl, const float* __restrict__ pv_m,
    const int* __restrict__ context, const int* __restrict__ glo2loc, const int* __restrict__ tp_path,
    float* __restrict__ out0, float* __restrict__ out1, short* __restrict__ Abuf, int step)
{
  const int b = blockIdx.x, t = threadIdx.x;
  const int w = t>>6, lane = t&63;
  __shared__ float pl[V_];
  __shared__ float red[16];
  __shared__ float pvp[16];
  float4 gv[2];
  const float4* g4 = (const float4*)(gen + (size_t)b*V_);
  float lm = -3.4e38f;
  #pragma unroll
  for (int i=0;i<2;i++){
    float4 g = g4[t + 1024*i];
    g.x*=INV32; g.y*=INV32; g.z*=INV32; g.w*=INV32;
    gv[i] = g;
    lm = fmaxf(lm, fmaxf(fmaxf(g.x,g.y), fmaxf(g.z,g.w)));
  }
  if (t < 544) lm = fmaxf(lm, cl[b*544+t]);
  #pragma unroll
  for (int off=32; off; off>>=1) lm = fmaxf(lm, __shfl_down(lm, off, 64));
  if (lane==0) red[w] = lm;
  __syncthreads();
  float m = red[0];
  #pragma unroll
  for (int i=1;i<16;i++) m = fmaxf(m, red[i]);
  __syncthreads();
  float ls = 0.f;
  #pragma unroll
  for (int i=0;i<2;i++){
    gv[i].x = expf(gv[i].x - m); gv[i].y = expf(gv[i].y - m);
    gv[i].z = expf(gv[i].z - m); gv[i].w = expf(gv[i].w - m);
    ls += gv[i].x + gv[i].y + gv[i].z + gv[i].w;
  }
  if (t < 544) ls += expf(cl[b*544+t] - m);
  #pragma unroll
  for (int off=32; off; off>>=1) ls += __shfl_down(ls, off, 64);
  if (lane==0) red[w] = ls;
  __syncthreads();
  float Z = red[0];
  #pragma unroll
  for (int i=1;i<16;i++) Z += red[i];
  const float invZ = 1.f / Z;
  if (t < 16) pvp[t] = expf(cl[b*544 + 512 + t] - m) * invZ;
  __syncthreads();
  #pragma unroll
  for (int i=0;i<2;i++){ gv[i].x*=invZ; gv[i].y*=invZ; gv[i].z*=invZ; gv[i].w*=invZ; }
  for (int l=0;l<16;l++){
    float wl = pvp[l];
    const float4* pv4 = (const float4*)(pv_m + (size_t)(b*16+l)*V_);
    #pragma unroll
    for (int i=0;i<2;i++){
      float4 q = pv4[t + 1024*i];
      gv[i].x += wl*q.x; gv[i].y += wl*q.y; gv[i].z += wl*q.z; gv[i].w += wl*q.w;
    }
  }
  #pragma unroll
  for (int i=0;i<2;i++) ((float4*)pl)[t + 1024*i] = gv[i];
  __syncthreads();
  if (t < 528){
    float val; int tgt;
    if (t < 512){
      val = expf(cl[b*544 + t] - m) * invZ;
      tgt = glo2loc[context[b*LC_ + t]];
    } else {
      int l = t - 512;
      val = expf(cl[b*544 + 528 + l] - m) * invZ;
      tgt = tp_path[b*16 + l];
    }
    if (val != 0.f) atomicAdd(&pl[tgt], val);
  }
  __syncthreads();
  // out0 + gumbel sample
  float* o0 = out0 + (size_t)(b*PREF_+step)*V_;
  uint32_t kx = 0u, ky = (uint32_t)step;
  tf2x32(0u, 42u, kx, ky);
  float lv[8];
  float lm2 = -3.4e38f;
  #pragma unroll
  for (int i=0;i<2;i++){
    float4 p4 = ((const float4*)pl)[t + 1024*i];
    ((float4*)o0)[t + 1024*i] = p4;
    float pe[4] = {p4.x, p4.y, p4.z, p4.w};
    #pragma unroll
    for (int k=0;k<4;k++){
      int v = 4*(t + 1024*i) + k;
      uint32_t j = (uint32_t)(b*V_ + v);
      uint32_t x0 = 0u, x1 = j;
      tf2x32(kx, ky, x0, x1);
      uint32_t bits = x0 ^ x1;
      float f = __uint_as_float((bits >> 9) | 0x3F800000u) - 1.0f;
      float u = fmaxf(1e-10f, f + 1e-10f);
      float g = -logf(-logf(u));
      float l = (logf(pe[k] + 1e-10f) + g) / 0.67f;
      lv[4*i+k] = l;
      lm2 = fmaxf(lm2, l);
    }
  }
  #pragma unroll
  for (int off=32; off; off>>=1) lm2 = fmaxf(lm2, __shfl_down(lm2, off, 64));
  if (lane==0) red[w] = lm2;
  __syncthreads();
  float m2 = red[0];
  #pragma unroll
  for (int i=1;i<16;i++) m2 = fmaxf(m2, red[i]);
  __syncthreads();
  float ls2 = 0.f;
  #pragma unroll
  for (int i=0;i<8;i++){ lv[i] = expf(lv[i] - m2); ls2 += lv[i]; }
  #pragma unroll
  for (int off=32; off; off>>=1) ls2 += __shfl_down(ls2, off, 64);
  if (lane==0) red[w] = ls2;
  __syncthreads();
  float Z2 = red[0];
  #pragma unroll
  for (int i=1;i<16;i++) Z2 += red[i];
  float* y = out1 + (size_t)(b*PREF_ + step)*V_;
  short* ab = Abuf + (size_t)b*KA_;
  #pragma unroll
  for (int i=0;i<2;i++){
    float4 y4; y4.x = lv[4*i]/Z2; y4.y = lv[4*i+1]/Z2; y4.z = lv[4*i+2]/Z2; y4.w = lv[4*i+3]/Z2;
    ((float4*)y)[t + 1024*i] = y4;
    short4 s4; s4.x=f2bf(y4.x); s4.y=f2bf(y4.y); s4.z=f2bf(y4.z); s4.w=f2bf(y4.w);
    *(short4*)(ab + 4*(t + 1024*i)) = s4;
  }
}

// ---------------- host ----------------
extern "C" void kernel_launch(void* const* d_in, const int* in_sizes, int n_in,
                              void* d_out, int out_size, void* d_ws, size_t ws_size,
                              hipStream_t stream)
{
  (void)in_sizes; (void)n_in; (void)out_size; (void)ws_size;
  const int*   context   = (const int*)  d_in[0];
  const int*   ctx_len   = (const int*)  d_in[1];
  const float* pv_m      = (const float*)d_in[2];
  const float* pv_mask   = (const float*)d_in[3];
  const int*   ar_len    = (const int*)  d_in[5];
  const int*   tp_path   = (const int*)  d_in[6];
  const int*   tp_len    = (const int*)  d_in[7];
  const float* tp_hidden = (const float*)d_in[8];
  const float* ar_hidden = (const float*)d_in[9];
  const float* E_ctx     = (const float*)d_in[10];
  const float* W_p       = (const float*)d_in[11];
  const float* E_topic   = (const float*)d_in[12];
  const float* W_q       = (const float*)d_in[13];
  const float* W_k       = (const float*)d_in[14];
  const float* W_v       = (const float*)d_in[15];
  const float* W_o       = (const float*)d_in[16];
  const float* gen_W     = (const float*)d_in[17];
  const float* gen_b     = (const float*)d_in[18];
  const int*   glo2loc   = (const int*)  d_in[19];

  float* out0 = (float*)d_out;
  float* out1 = out0 + (size_t)B_*PREF_*V_;

  // ---- workspace layout ----
  short* sw      = (short*)d_ws;
  short* EtM_pk  = sw;  sw += (size_t)8192*1024;     // E_topic @ Wq @ Wk^T, packed
  short* WoStack = sw;  sw += (size_t)KA_*1024;      // [E_topic@Wo ; Wv@Wo], packed
  short* genW_pk = sw;  sw += (size_t)1024*8192;
  short* Abuf    = sw;  sw += (size_t)B_*KA_;        // [y | asrc] bf16
  short* dtan    = sw;  sw += (size_t)B_*H_;
  short* src_bf  = sw;  sw += (size_t)B_*SP_*H_;     // materialized src_hidden bf16
  short* pvm_bf  = src_bf;                            // setup-only aliases (freed by src_build)
  short* Wp_pk   = src_bf + (size_t)1024*8192;
  float* fw      = (float*)sw;
  float* smask   = fw;  fw += B_*SP_;
  float* Mw      = fw;  fw += 1024*1024;
  float* pvh     = fw;  fw += 1024*1024;
  float* qk      = fw;  fw += B_*H_;                 // -- zero region start --
  float* decr    = fw;  fw += B_*H_;
  float* gen     = fw;  fw += (size_t)B_*V_;         // -- zero region end --
  float* part_o  = fw;  fw += (size_t)B_*8*H_;
  float* part_ml = fw;  fw += B_*8*2;
  float* cl      = fw;  fw += B_*544;
  const size_t zbytes = (size_t)(2*B_*H_ + B_*V_) * sizeof(float);

  // ---- one-time setup ----
  hipMemsetAsync(pvh, 0, (size_t)1024*1024*sizeof(float), stream);
  cast_bf  <<<dim3(8192), dim3(256), 0, stream>>>(pv_m, pvm_bf);          // 1024x8192 (full coverage)
  cast_pack<<<dim3(8192), dim3(256), 0, stream>>>(W_p, Wp_pk, 1024);      // K=8192,N=1024
  bgemm<128,true,false><<<dim3(8,8,4), dim3(256), 0, stream>>>(
      pvm_bf, 8192, Wp_pk, 1024, pvh, 1024, 2048, nullptr);               // pv_hidden
  mgemm<true,false><<<dim3(8,8,1), dim3(256), 0, stream>>>(
      W_q, H_, W_k, H_, Mw, H_, H_);                                      // Mw = Wq@Wk^T
  mgemm<false,true><<<dim3(8,64,1), dim3(256), 0, stream>>>(
      E_topic, H_, Mw, H_, (float*)EtM_pk, H_, H_);                       // EtM packed
  mgemm<false,true><<<dim3(8,64,1), dim3(256), 0, stream>>>(
      E_topic, H_, W_o, H_, (float*)WoStack, H_, H_);                     // EtWo -> rows 0..8191
  mgemm<false,true><<<dim3(8,8,1), dim3(256), 0, stream>>>(
      W_v, H_, W_o, H_, (float*)(WoStack + (size_t)8192*1024), H_, H_);   // Wvo -> rows 8192..9215
  cast_pack<<<dim3(8192), dim3(256), 0, stream>>>(gen_W, genW_pk, 8192);  // K=1024,N=8192
  src_build<<<dim3(64,280), dim3(256), 0, stream>>>(
      E_ctx, context, ctx_len, pvh, pv_mask, tp_hidden, tp_len, ar_hidden, ar_len, src_bf, smask);
  abuf_init<<<dim3(36,64), dim3(256), 0, stream>>>(Abuf);

  // ---- decode loop ----
  for (int t = 0; t < PREF_; ++t){
    hipMemsetAsync(qk, 0, zbytes, stream);
    // qk = y @ EtM   (K=8192)
    bgemm<64,true,false><<<dim3(8,1,16), dim3(256), 0, stream>>>(
        Abuf, KA_, EtM_pk, H_, qk, H_, 512, nullptr);
    // attention
    attn_pass<<<dim3(64,8), dim3(256), 0, stream>>>(qk, src_bf, smask, part_o, part_ml);
    attn_combine<<<dim3(64), dim3(256), 0, stream>>>(part_o, part_ml, Abuf);
    // decr = [y|asrc] @ [EtWo;Wvo]  (K=9216)
    bgemm<64,true,false><<<dim3(8,1,18), dim3(256), 0, stream>>>(
        Abuf, KA_, WoStack, H_, decr, H_, 512, nullptr);
    tanhcast<<<dim3(64), dim3(256), 0, stream>>>(decr, dtan);
    // gen = tanh(decr) @ gen_W + b  (K=1024, N=8192)
    bgemm<64,true,true><<<dim3(64,1,2), dim3(256), 0, stream>>>(
        dtan, H_, genW_pk, V_, gen, V_, 512, gen_b);
    // copy logits
    copy_score<<<dim3(64,8), dim3(256), 0, stream>>>(dtan, src_bf, smask, cl);
    // softmax stats + p + scatter + sample (fused)
    fuse_out<<<dim3(64), dim3(1024), 0, stream>>>(
        gen, cl, pv_m, context, glo2loc, tp_path, out0, out1, Abuf, t);
  }
}

// Round 2
// 2720.191 us; speedup vs baseline: 1.2284x; 1.1116x over previous
//
#include <hip/hip_runtime.h>
#include <hip/hip_bf16.h>
#include <stdint.h>

#define B_    64
#define LC_   512
#define V_    8192
#define H_    1024
#define PREF_ 16
#define S_    545
#define SP_   560          // padded src rows (545 -> 560 = 35*16)
#define NEGV  (-1e9f)
#define INV32 0.03125f     // H^-0.5

typedef __attribute__((ext_vector_type(8))) short s8v;   // 8 bf16 MFMA frag
typedef __attribute__((ext_vector_type(4))) float f4a;   // MFMA C/D frag

__device__ __forceinline__ short f2bf(float f){
  uint32_t u = __float_as_uint(f);
  uint32_t r = (u + 0x7fffu + ((u >> 16) & 1u)) >> 16;
  return (short)(r & 0xffffu);
}
__device__ __forceinline__ float bf2f(short s){
  return __uint_as_float(((uint32_t)(uint16_t)s) << 16);
}

// ---------------- threefry2x32 (exact JAX semantics) ----------------
__device__ __forceinline__ uint32_t rotl32(uint32_t x, uint32_t d){ return (x<<d)|(x>>(32u-d)); }
__device__ __forceinline__ void tf2x32(uint32_t k0, uint32_t k1, uint32_t& x0, uint32_t& x1){
  uint32_t ks0=k0, ks1=k1, ks2=k0^k1^0x1BD11BDAu;
  x0+=ks0; x1+=ks1;
  x0+=x1; x1=rotl32(x1,13); x1^=x0;
  x0+=x1; x1=rotl32(x1,15); x1^=x0;
  x0+=x1; x1=rotl32(x1,26); x1^=x0;
  x0+=x1; x1=rotl32(x1, 6); x1^=x0;
  x0+=ks1; x1+=ks2+1u;
  x0+=x1; x1=rotl32(x1,17); x1^=x0;
  x0+=x1; x1=rotl32(x1,29); x1^=x0;
  x0+=x1; x1=rotl32(x1,16); x1^=x0;
  x0+=x1; x1=rotl32(x1,24); x1^=x0;
  x0+=ks2; x1+=ks0+2u;
  x0+=x1; x1=rotl32(x1,13); x1^=x0;
  x0+=x1; x1=rotl32(x1,15); x1^=x0;
  x0+=x1; x1=rotl32(x1,26); x1^=x0;
  x0+=x1; x1=rotl32(x1, 6); x1^=x0;
  x0+=ks0; x1+=ks1+3u;
  x0+=x1; x1=rotl32(x1,17); x1^=x0;
  x0+=x1; x1=rotl32(x1,29); x1^=x0;
  x0+=x1; x1=rotl32(x1,16); x1^=x0;
  x0+=x1; x1=rotl32(x1,24); x1^=x0;
  x0+=ks1; x1+=ks2+4u;
  x0+=x1; x1=rotl32(x1,13); x1^=x0;
  x0+=x1; x1=rotl32(x1,15); x1^=x0;
  x0+=x1; x1=rotl32(x1,26); x1^=x0;
  x0+=x1; x1=rotl32(x1, 6); x1^=x0;
  x0+=ks2; x1+=ks0+5u;
}

// ---------------- casts ----------------
__global__ __launch_bounds__(256) void cast_bf(const float* __restrict__ in, short* __restrict__ out){
  size_t idx = ((size_t)blockIdx.x*256 + threadIdx.x)*4;
  float4 v = *(const float4*)(in+idx);
  short4 s; s.x=f2bf(v.x); s.y=f2bf(v.y); s.z=f2bf(v.z); s.w=f2bf(v.w);
  *(short4*)(out+idx) = s;
}
// fp32 [K][N] -> k-packeted bf16: off(k,n) = ((k>>3)*N + n)*8 + (k&7)
__global__ __launch_bounds__(256) void cast_pack(const float* __restrict__ in, short* __restrict__ out, int N){
  int gid = blockIdx.x*256 + threadIdx.x;
  int k = gid / (N>>2);
  int n = (gid % (N>>2))*4;
  float4 v = *(const float4*)(in + (size_t)k*N + n);
  size_t base = ((size_t)(k>>3)*N + n)*8 + (k&7);
  out[base] = f2bf(v.x); out[base+8] = f2bf(v.y); out[base+16] = f2bf(v.z); out[base+24] = f2bf(v.w);
}
// emb fp32 [64][1024] -> EA bf16 row-major lda 2048, cols 0..1023
__global__ __launch_bounds__(256) void embcast(const float* __restrict__ emb, short* __restrict__ EA){
  int idx = blockIdx.x*256 + threadIdx.x;     // grid 64 -> 16384 float4
  int row = idx >> 8, c4 = idx & 255;
  float4 v = ((const float4*)(emb + (size_t)row*1024))[c4];
  short4 s; s.x=f2bf(v.x); s.y=f2bf(v.y); s.z=f2bf(v.z); s.w=f2bf(v.w);
  *(short4*)(EA + (size_t)row*2048 + c4*4) = s;
}

// ---------------- bf16-in GEMM: A row-major bf16 (direct-global frags), B k-packeted bf16 ----------------
template<int BM, bool ATOMIC, bool BIAS>
__global__ __launch_bounds__(256) void bgemm(
    const short* __restrict__ A, int lda,
    const short* __restrict__ Bp, int ldn,
    float* __restrict__ C, int ldc,
    int kchunk, const float* __restrict__ bias)
{
  constexpr int BN = 128, BK = 64;
  __shared__ short Bl[BK*BN];
  const int t = threadIdx.x;
  const int w = t >> 6, lane = t & 63;
  const int quad = lane >> 4, l16 = lane & 15;
  const int col0 = blockIdx.x * BN;
  const int row0 = (BM==128) ? blockIdx.y * BM : 0;
  const int k0 = blockIdx.z * kchunk, kend = k0 + kchunk;
  constexpr int MT = 2;
  constexpr int NT = (BM==128) ? 8 : 4;
  const int mbase = (BM==128) ? w*32 : (w&1)*32;
  const int nbase = (BM==128) ? 0 : (w>>1)*64;
  f4a acc[MT][NT];
  #pragma unroll
  for (int mt=0; mt<MT; mt++)
    #pragma unroll
    for (int nt=0; nt<NT; nt++)
      acc[mt][nt] = (f4a){0.f,0.f,0.f,0.f};

  for (int kb = k0; kb < kend; kb += BK){
    #pragma unroll
    for (int i=0;i<4;i++){                      // stage B tile: 1024 short8
      int idx = t + i*256;
      int p = idx >> 7, n = idx & 127;
      ((s8v*)Bl)[idx] = *(const s8v*)(Bp + (((size_t)((kb>>3)+p))*ldn + col0 + n)*8);
    }
    __syncthreads();
    #pragma unroll
    for (int ks=0; ks<BK; ks+=32){
      const int kk = kb + ks + quad*8;
      const int kl = ks + quad*8;
      s8v af[MT], bfr[NT];
      #pragma unroll
      for (int mt=0; mt<MT; mt++)
        af[mt] = *(const s8v*)(A + (size_t)(row0+mbase+mt*16+l16)*lda + kk);
      #pragma unroll
      for (int nt=0; nt<NT; nt++)
        bfr[nt] = *(const s8v*)&Bl[((kl>>3)*BN + nbase + nt*16 + l16)*8];
      #pragma unroll
      for (int mt=0; mt<MT; mt++)
        #pragma unroll
        for (int nt=0; nt<NT; nt++)
          acc[mt][nt] = __builtin_amdgcn_mfma_f32_16x16x32_bf16(af[mt], bfr[nt], acc[mt][nt], 0, 0, 0);
    }
    __syncthreads();
  }
  #pragma unroll
  for (int mt=0; mt<MT; mt++){
    #pragma unroll
    for (int nt=0; nt<NT; nt++){
      #pragma unroll
      for (int r=0; r<4; r++){
        int row = row0 + mbase + mt*16 + quad*4 + r;
        int cc  = col0 + nbase + nt*16 + l16;
        float v = acc[mt][nt][r];
        if (BIAS){ if (!ATOMIC || blockIdx.z==0) v += bias[cc]; }
        size_t idx = (size_t)row*ldc + cc;
        if (ATOMIC) atomicAdd(&C[idx], v);
        else        C[idx] = v;
      }
    }
  }
}

// ---------------- fp32-in GEMM (setup only), BM=128; PACK: bf16 k-packeted output ----------------
template<bool TRANSB, bool PACK>
__global__ __launch_bounds__(256) void mgemm(
    const float* __restrict__ A, int lda,
    const float* __restrict__ Bm, int ldb,
    float* __restrict__ C, int ldc, int K)
{
  constexpr int BM = 128, BN = 128, BK = 64;
  __shared__ short Ap[BK*BM];
  __shared__ short Bp[BK*BN];
  const int t = threadIdx.x;
  const int w = t >> 6, lane = t & 63;
  const int quad = lane >> 4, l16 = lane & 15;
  const int col0 = blockIdx.x * BN;
  const int row0 = blockIdx.y * BM;
  constexpr int MT = 2, NT = 8;
  const int mbase = w*32, nbase = 0;
  f4a acc[MT][NT];
  #pragma unroll
  for (int mt=0; mt<MT; mt++)
    #pragma unroll
    for (int nt=0; nt<NT; nt++)
      acc[mt][nt] = (f4a){0.f,0.f,0.f,0.f};

  for (int kb = 0; kb < K; kb += BK){
    #pragma unroll
    for (int i = 0; i < 8; ++i){
      int idx = t + i*256;
      int m = idx >> 4, kq = (idx & 15) * 4;
      float4 a = *(const float4*)(A + (size_t)(row0+m)*lda + kb + kq);
      short4 s4; s4.x=f2bf(a.x); s4.y=f2bf(a.y); s4.z=f2bf(a.z); s4.w=f2bf(a.w);
      *(short4*)&Ap[((kq>>3)*BM + m)*8 + (kq&7)] = s4;
    }
    if (TRANSB){
      #pragma unroll
      for (int i = 0; i < 8; ++i){
        int idx = t + i*256;
        int n = idx >> 4, kq = (idx & 15) * 4;
        float4 bv = *(const float4*)(Bm + (size_t)(col0+n)*ldb + kb + kq);
        short4 s4; s4.x=f2bf(bv.x); s4.y=f2bf(bv.y); s4.z=f2bf(bv.z); s4.w=f2bf(bv.w);
        *(short4*)&Bp[((kq>>3)*BN + n)*8 + (kq&7)] = s4;
      }
    } else {
      #pragma unroll
      for (int c = 0; c < 8; ++c){
        int idx = t + c*256;
        int n = idx & 127, kq = (idx >> 7) * 4;
        const float* bp0 = Bm + (size_t)(kb+kq)*ldb + col0 + n;
        float b0 = bp0[0], b1 = bp0[ldb], b2 = bp0[2*(size_t)ldb], b3 = bp0[3*(size_t)ldb];
        short4 s4; s4.x=f2bf(b0); s4.y=f2bf(b1); s4.z=f2bf(b2); s4.w=f2bf(b3);
        *(short4*)&Bp[((kq>>3)*BN + n)*8 + (kq&7)] = s4;
      }
    }
    __syncthreads();
    #pragma unroll
    for (int ks = 0; ks < BK; ks += 32){
      const int kk = ks + quad*8;
      s8v af[MT], bfr[NT];
      #pragma unroll
      for (int mt=0; mt<MT; mt++)
        af[mt] = *(const s8v*)&Ap[((kk>>3)*BM + mbase + mt*16 + l16)*8];
      #pragma unroll
      for (int nt=0; nt<NT; nt++)
        bfr[nt] = *(const s8v*)&Bp[((kk>>3)*BN + nbase + nt*16 + l16)*8];
      #pragma unroll
      for (int mt=0; mt<MT; mt++)
        #pragma unroll
        for (int nt=0; nt<NT; nt++)
          acc[mt][nt] = __builtin_amdgcn_mfma_f32_16x16x32_bf16(af[mt], bfr[nt], acc[mt][nt], 0, 0, 0);
    }
    __syncthreads();
  }
  #pragma unroll
  for (int mt=0; mt<MT; mt++){
    #pragma unroll
    for (int nt=0; nt<NT; nt++){
      #pragma unroll
      for (int r=0; r<4; r++){
        int row = row0 + mbase + mt*16 + quad*4 + r;
        int cc  = col0 + nbase + nt*16 + l16;
        float v = acc[mt][nt][r];
        if (PACK){
          size_t off = (((size_t)(row>>3))*ldc + cc)*8 + (row&7);
          ((short*)C)[off] = f2bf(v);
        } else {
          C[(size_t)row*ldc + cc] = v;
        }
      }
    }
  }
}

// ---------------- src_hidden materialization (bf16) + mask ----------------
// coalesced: block = 2 rows, 128 threads/row; masked/padding rows not written
// (all consumers are smask-guarded), only smask is written.
__global__ __launch_bounds__(256) void src_build(
    const float* __restrict__ E_ctx, const int* __restrict__ context, const int* __restrict__ ctx_len,
    const float* __restrict__ pvh, const float* __restrict__ pv_mask,
    const float* __restrict__ tp_hidden, const int* __restrict__ tp_len,
    const float* __restrict__ ar_hidden, const int* __restrict__ ar_len,
    short* __restrict__ src, float* __restrict__ smask)
{
  const int b = blockIdx.x, t = threadIdx.x;
  const int j = blockIdx.y*2 + (t >> 7);        // grid.y = 280 -> j in 0..559
  const int c = (t & 127) * 8;
  const float* srcp = nullptr;
  float msk = 0.f;
  if (j < 512){
    bool on = j < ctx_len[b];
    msk = on ? 1.f : 0.f;
    if (on) srcp = E_ctx + (size_t)context[b*LC_ + j]*H_;
  } else if (j < 528){
    srcp = pvh + (size_t)(b*16 + j-512)*H_;
    msk = pv_mask[b*16 + j-512];
  } else if (j < 544){
    srcp = tp_hidden + (size_t)(b*16 + j-528)*H_;
    msk = ((j-528) < tp_len[b]) ? 1.f : 0.f;
  } else if (j == 544){
    srcp = ar_hidden + (size_t)b*H_;
    msk = (ar_len[b] > 0) ? 1.f : 0.f;
  }
  if (srcp){
    float4 v0 = *(const float4*)(srcp + c);
    float4 v1 = *(const float4*)(srcp + c + 4);
    s8v s;
    s[0]=f2bf(v0.x); s[1]=f2bf(v0.y); s[2]=f2bf(v0.z); s[3]=f2bf(v0.w);
    s[4]=f2bf(v1.x); s[5]=f2bf(v1.y); s[6]=f2bf(v1.z); s[7]=f2bf(v1.w);
    *(s8v*)(src + (size_t)(b*SP_ + j)*H_ + c) = s;
  }
  if ((t & 127) == 0) smask[b*SP_ + j] = msk;
}

__global__ __launch_bounds__(256) void abuf_init(short* __restrict__ Abuf){
  int v = blockIdx.x*256 + threadIdx.x;  // grid (32, 64) -> v in 0..8191
  int b = blockIdx.y;
  Abuf[(size_t)b*V_ + v] = (v == 2) ? (short)0x3F80 : (short)0;
}

// ---------------- attention: flash chunk pass over bf16 src (16 chunks x 35 rows) ----------------
__global__ __launch_bounds__(256) void attn_pass(
    const float* __restrict__ qk, const short* __restrict__ src, const float* __restrict__ smask,
    float* __restrict__ part_o, float* __restrict__ part_ml)
{
  const int b = blockIdx.x, c = blockIdx.y, t = threadIdx.x;
  const int w = t>>6, lane = t&63;
  __shared__ float sv[35], pr[35], red[4];
  float qreg[16];
  {
    const float4* q4 = (const float4*)(qk + (size_t)b*H_ + lane*16);
    #pragma unroll
    for (int i=0;i<4;i++){ float4 v = q4[i]; qreg[4*i]=v.x; qreg[4*i+1]=v.y; qreg[4*i+2]=v.z; qreg[4*i+3]=v.w; }
  }
  const int j0 = c*35;
  for (int r = w; r < 35; r += 4){
    float msk = smask[b*SP_ + j0 + r];
    float s = -3.4e38f;
    if (msk != 0.f){
      const s8v* rp = (const s8v*)(src + (size_t)(b*SP_ + j0 + r)*H_);
      s8v v0 = rp[lane*2], v1 = rp[lane*2+1];
      float acc = 0.f;
      #pragma unroll
      for (int i=0;i<8;i++) acc += bf2f(v0[i])*qreg[i];
      #pragma unroll
      for (int i=0;i<8;i++) acc += bf2f(v1[i])*qreg[8+i];
      #pragma unroll
      for (int off=32; off; off>>=1) acc += __shfl_down(acc, off, 64);
      s = acc * INV32;
    }
    if (lane == 0) sv[r] = s;
  }
  __syncthreads();
  float lm = (t < 35) ? sv[t] : -3.4e38f;
  #pragma unroll
  for (int off=32; off; off>>=1) lm = fmaxf(lm, __shfl_down(lm, off, 64));
  if (lane==0) red[w] = lm;
  __syncthreads();
  const float m = fmaxf(fmaxf(red[0],red[1]), fmaxf(red[2],red[3]));
  __syncthreads();
  if (t < 35) pr[t] = (sv[t] > -1e37f) ? expf(sv[t]-m) : 0.f;
  __syncthreads();
  float ls = (t < 35) ? pr[t] : 0.f;
  #pragma unroll
  for (int off=32; off; off>>=1) ls += __shfl_down(ls, off, 64);
  if (lane==0) red[w] = ls;
  __syncthreads();
  const float lsum = red[0]+red[1]+red[2]+red[3];
  float4 o = {0.f,0.f,0.f,0.f};
  const short* base = src + (size_t)(b*SP_ + j0)*H_ + t*4;
  for (int r=0;r<35;r++){
    float p_ = pr[r];
    if (p_ != 0.f){
      short4 s4 = *(const short4*)(base + (size_t)r*H_);
      o.x += p_*bf2f(s4.x); o.y += p_*bf2f(s4.y); o.z += p_*bf2f(s4.z); o.w += p_*bf2f(s4.w);
    }
  }
  ((float4*)(part_o + (size_t)(b*16+c)*H_))[t] = o;
  if (t==0){ part_ml[(b*16+c)*2] = m; part_ml[(b*16+c)*2+1] = lsum; }
}

// combine 16 chunks -> asrc, written as bf16 into EA cols [1024..2047]
__global__ __launch_bounds__(256) void attn_combine(
    const float* __restrict__ part_o, const float* __restrict__ part_ml,
    short* __restrict__ EA)
{
  const int b = blockIdx.x, t = threadIdx.x;
  __shared__ float sm[16], sl[16];
  if (t < 16){ sm[t] = part_ml[(b*16+t)*2]; sl[t] = part_ml[(b*16+t)*2+1]; }
  __syncthreads();
  float M = -3.4e38f;
  #pragma unroll
  for (int i=0;i<16;i++) M = fmaxf(M, sm[i]);
  float wgt[16]; float Z = 0.f;
  #pragma unroll
  for (int i=0;i<16;i++){ wgt[i] = expf(sm[i]-M); Z += wgt[i]*sl[i]; }
  float4 o = {0.f,0.f,0.f,0.f};
  #pragma unroll
  for (int i=0;i<16;i++){
    float4 p = ((const float4*)(part_o + (size_t)(b*16+i)*H_))[t];
    o.x += wgt[i]*p.x; o.y += wgt[i]*p.y; o.z += wgt[i]*p.z; o.w += wgt[i]*p.w;
  }
  float inv = 1.f / Z;
  short4 s4; s4.x=f2bf(o.x*inv); s4.y=f2bf(o.y*inv); s4.z=f2bf(o.z*inv); s4.w=f2bf(o.w*inv);
  *(short4*)(EA + (size_t)b*2048 + 1024 + t*4) = s4;
}

// dtan = bf16(tanh(decr))
__global__ __launch_bounds__(256) void tanhcast(const float* __restrict__ decr, short* __restrict__ dtan){
  int idx = blockIdx.x*256 + threadIdx.x;   // grid 64 -> 16384 float4
  float4 v = ((const float4*)decr)[idx];
  short4 s; s.x=f2bf(tanhf(v.x)); s.y=f2bf(tanhf(v.y)); s.z=f2bf(tanhf(v.z)); s.w=f2bf(tanhf(v.w));
  ((short4*)dtan)[idx] = s;
}

// ---------------- copy logits over bf16 src (16 chunks x 34 rows) ----------------
__global__ __launch_bounds__(256) void copy_score(
    const short* __restrict__ dtan, const short* __restrict__ src, const float* __restrict__ smask,
    float* __restrict__ cl)
{
  const int b = blockIdx.x, c = blockIdx.y, t = threadIdx.x;
  const int w = t>>6, lane = t&63;
  float qd[16];
  {
    const s8v* d8 = (const s8v*)(dtan + (size_t)b*H_ + lane*16);
    s8v d0 = d8[0], d1 = d8[1];
    #pragma unroll
    for (int i=0;i<8;i++){ qd[i] = bf2f(d0[i]); qd[8+i] = bf2f(d1[i]); }
  }
  for (int r = w; r < 34; r += 4){
    int j = c*34 + r;
    float msk = smask[b*SP_ + j];
    float s;
    if (msk != 0.f){
      const s8v* rp = (const s8v*)(src + (size_t)(b*SP_ + j)*H_);
      s8v v0 = rp[lane*2], v1 = rp[lane*2+1];
      float acc = 0.f;
      #pragma unroll
      for (int i=0;i<8;i++) acc += bf2f(v0[i])*qd[i];
      #pragma unroll
      for (int i=0;i<8;i++) acc += bf2f(v1[i])*qd[8+i];
      #pragma unroll
      for (int off=32; off; off>>=1) acc += __shfl_down(acc, off, 64);
      s = acc * INV32;
    } else s = NEGV * INV32;
    if (lane == 0) cl[b*544 + j] = s;
  }
}

// ---------------- fused: softmax stats + p build + scatter + gumbel sample ----------------
__global__ __launch_bounds__(1024) void fuse_out(
    const float* __restrict__ gen, const float* __restrict__ cl, const float* __restrict__ pv_m,
    const int* __restrict__ context, const int* __restrict__ glo2loc, const int* __restrict__ tp_path,
    float* __restrict__ out0, float* __restrict__ out1, short* __restrict__ Abuf, int step)
{
  const int b = blockIdx.x, t = threadIdx.x;
  const int w = t>>6, lane = t&63;
  __shared__ float pl[V_];
  __shared__ float red[16];
  __shared__ float pvp[16];
  float4 gv[2];
  const float4* g4 = (const float4*)(gen + (size_t)b*V_);
  float lm = -3.4e38f;
  #pragma unroll
  for (int i=0;i<2;i++){
    float4 g = g4[t + 1024*i];
    g.x*=INV32; g.y*=INV32; g.z*=INV32; g.w*=INV32;
    gv[i] = g;
    lm = fmaxf(lm, fmaxf(fmaxf(g.x,g.y), fmaxf(g.z,g.w)));
  }
  if (t < 544) lm = fmaxf(lm, cl[b*544+t]);
  #pragma unroll
  for (int off=32; off; off>>=1) lm = fmaxf(lm, __shfl_down(lm, off, 64));
  if (lane==0) red[w] = lm;
  __syncthreads();
  float m = red[0];
  #pragma unroll
  for (int i=1;i<16;i++) m = fmaxf(m, red[i]);
  __syncthreads();
  float ls = 0.f;
  #pragma unroll
  for (int i=0;i<2;i++){
    gv[i].x = expf(gv[i].x - m); gv[i].y = expf(gv[i].y - m);
    gv[i].z = expf(gv[i].z - m); gv[i].w = expf(gv[i].w - m);
    ls += gv[i].x + gv[i].y + gv[i].z + gv[i].w;
  }
  if (t < 544) ls += expf(cl[b*544+t] - m);
  #pragma unroll
  for (int off=32; off; off>>=1) ls += __shfl_down(ls, off, 64);
  if (lane==0) red[w] = ls;
  __syncthreads();
  float Z = red[0];
  #pragma unroll
  for (int i=1;i<16;i++) Z += red[i];
  const float invZ = 1.f / Z;
  if (t < 16) pvp[t] = expf(cl[b*544 + 512 + t] - m) * invZ;
  __syncthreads();
  #pragma unroll
  for (int i=0;i<2;i++){ gv[i].x*=invZ; gv[i].y*=invZ; gv[i].z*=invZ; gv[i].w*=invZ; }
  for (int l=0;l<16;l++){
    float wl = pvp[l];
    const float4* pv4 = (const float4*)(pv_m + (size_t)(b*16+l)*V_);
    #pragma unroll
    for (int i=0;i<2;i++){
      float4 q = pv4[t + 1024*i];
      gv[i].x += wl*q.x; gv[i].y += wl*q.y; gv[i].z += wl*q.z; gv[i].w += wl*q.w;
    }
  }
  #pragma unroll
  for (int i=0;i<2;i++) ((float4*)pl)[t + 1024*i] = gv[i];
  __syncthreads();
  if (t < 528){
    float val; int tgt;
    if (t < 512){
      val = expf(cl[b*544 + t] - m) * invZ;
      tgt = glo2loc[context[b*LC_ + t]];
    } else {
      int l = t - 512;
      val = expf(cl[b*544 + 528 + l] - m) * invZ;
      tgt = tp_path[b*16 + l];
    }
    if (val != 0.f) atomicAdd(&pl[tgt], val);
  }
  __syncthreads();
  // out0 + gumbel sample
  float* o0 = out0 + (size_t)(b*PREF_+step)*V_;
  uint32_t kx = 0u, ky = (uint32_t)step;
  tf2x32(0u, 42u, kx, ky);
  float lv[8];
  float lm2 = -3.4e38f;
  #pragma unroll
  for (int i=0;i<2;i++){
    float4 p4 = ((const float4*)pl)[t + 1024*i];
    ((float4*)o0)[t + 1024*i] = p4;
    float pe[4] = {p4.x, p4.y, p4.z, p4.w};
    #pragma unroll
    for (int k=0;k<4;k++){
      int v = 4*(t + 1024*i) + k;
      uint32_t j = (uint32_t)(b*V_ + v);
      uint32_t x0 = 0u, x1 = j;
      tf2x32(kx, ky, x0, x1);
      uint32_t bits = x0 ^ x1;
      float f = __uint_as_float((bits >> 9) | 0x3F800000u) - 1.0f;
      float u = fmaxf(1e-10f, f + 1e-10f);
      float g = -logf(-logf(u));
      float l = (logf(pe[k] + 1e-10f) + g) / 0.67f;
      lv[4*i+k] = l;
      lm2 = fmaxf(lm2, l);
    }
  }
  #pragma unroll
  for (int off=32; off; off>>=1) lm2 = fmaxf(lm2, __shfl_down(lm2, off, 64));
  if (lane==0) red[w] = lm2;
  __syncthreads();
  float m2 = red[0];
  #pragma unroll
  for (int i=1;i<16;i++) m2 = fmaxf(m2, red[i]);
  __syncthreads();
  float ls2 = 0.f;
  #pragma unroll
  for (int i=0;i<8;i++){ lv[i] = expf(lv[i] - m2); ls2 += lv[i]; }
  #pragma unroll
  for (int off=32; off; off>>=1) ls2 += __shfl_down(ls2, off, 64);
  if (lane==0) red[w] = ls2;
  __syncthreads();
  float Z2 = red[0];
  #pragma unroll
  for (int i=1;i<16;i++) Z2 += red[i];
  float* y = out1 + (size_t)(b*PREF_ + step)*V_;
  short* ab = Abuf + (size_t)b*V_;
  #pragma unroll
  for (int i=0;i<2;i++){
    float4 y4; y4.x = lv[4*i]/Z2; y4.y = lv[4*i+1]/Z2; y4.z = lv[4*i+2]/Z2; y4.w = lv[4*i+3]/Z2;
    ((float4*)y)[t + 1024*i] = y4;
    short4 s4; s4.x=f2bf(y4.x); s4.y=f2bf(y4.y); s4.z=f2bf(y4.z); s4.w=f2bf(y4.w);
    *(short4*)(ab + 4*(t + 1024*i)) = s4;
  }
}

// ---------------- host ----------------
extern "C" void kernel_launch(void* const* d_in, const int* in_sizes, int n_in,
                              void* d_out, int out_size, void* d_ws, size_t ws_size,
                              hipStream_t stream)
{
  (void)in_sizes; (void)n_in; (void)out_size; (void)ws_size;
  const int*   context   = (const int*)  d_in[0];
  const int*   ctx_len   = (const int*)  d_in[1];
  const float* pv_m      = (const float*)d_in[2];
  const float* pv_mask   = (const float*)d_in[3];
  const int*   ar_len    = (const int*)  d_in[5];
  const int*   tp_path   = (const int*)  d_in[6];
  const int*   tp_len    = (const int*)  d_in[7];
  const float* tp_hidden = (const float*)d_in[8];
  const float* ar_hidden = (const float*)d_in[9];
  const float* E_ctx     = (const float*)d_in[10];
  const float* W_p       = (const float*)d_in[11];
  const float* E_topic   = (const float*)d_in[12];
  const float* W_q       = (const float*)d_in[13];
  const float* W_k       = (const float*)d_in[14];
  const float* W_v       = (const float*)d_in[15];
  const float* W_o       = (const float*)d_in[16];
  const float* gen_W     = (const float*)d_in[17];
  const float* gen_b     = (const float*)d_in[18];
  const int*   glo2loc   = (const int*)  d_in[19];

  float* out0 = (float*)d_out;
  float* out1 = out0 + (size_t)B_*PREF_*V_;

  // ---- workspace layout ----
  short* sw      = (short*)d_ws;
  short* Etp_pk  = sw;  sw += (size_t)8192*1024;     // E_topic, k-packeted (K=8192,N=1024)
  short* genW_pk = sw;  sw += (size_t)1024*8192;     // gen_W packed (K=1024,N=8192)
  short* WoV_pk  = sw;  sw += (size_t)2048*1024;     // [W_o ; W_v@W_o] packed (K=2048,N=1024)
  short* Mw_pk   = sw;  sw += (size_t)1024*1024;     // Wq@Wk^T packed (K=1024,N=1024)
  short* Abuf    = sw;  sw += (size_t)B_*V_;         // y bf16 (64x8192)
  short* EA      = sw;  sw += (size_t)B_*2048;       // [emb | asrc] bf16 (64x2048)
  short* dtan    = sw;  sw += (size_t)B_*H_;
  short* src_bf  = sw;  sw += (size_t)B_*SP_*H_;     // materialized src_hidden bf16
  short* pvm_bf  = src_bf;                            // setup-only aliases (freed by src_build)
  short* Wp_pk   = src_bf + (size_t)1024*8192;
  float* fw      = (float*)sw;
  float* smask   = fw;  fw += B_*SP_;
  float* pvh     = fw;  fw += 1024*1024;
  float* emb     = fw;  fw += B_*H_;                 // -- zero region start --
  float* qk      = fw;  fw += B_*H_;
  float* decr    = fw;  fw += B_*H_;                 // -- zero region end --
  float* gen     = fw;  fw += (size_t)B_*V_;         // non-atomic, no memset needed
  float* part_o  = fw;  fw += (size_t)B_*16*H_;
  float* part_ml = fw;  fw += B_*16*2;
  float* cl      = fw;  fw += B_*544;
  const size_t zbytes = (size_t)(3*B_*H_) * sizeof(float);

  // ---- one-time setup ----
  hipMemsetAsync(pvh, 0, (size_t)1024*1024*sizeof(float), stream);
  cast_bf  <<<dim3(8192), dim3(256), 0, stream>>>(pv_m, pvm_bf);          // 1024x8192
  cast_pack<<<dim3(8192), dim3(256), 0, stream>>>(W_p, Wp_pk, 1024);      // K=8192,N=1024
  bgemm<128,true,false><<<dim3(8,8,4), dim3(256), 0, stream>>>(
      pvm_bf, 8192, Wp_pk, 1024, pvh, 1024, 2048, nullptr);               // pv_hidden
  mgemm<true,true><<<dim3(8,8,1), dim3(256), 0, stream>>>(
      W_q, H_, W_k, H_, (float*)Mw_pk, H_, H_);                           // Mw = Wq@Wk^T, packed
  cast_pack<<<dim3(1024), dim3(256), 0, stream>>>(W_o, WoV_pk, 1024);     // Wo -> rows 0..1023
  mgemm<false,true><<<dim3(8,8,1), dim3(256), 0, stream>>>(
      W_v, H_, W_o, H_, (float*)(WoV_pk + (size_t)1024*1024), H_, H_);    // Wv@Wo -> rows 1024..2047
  cast_pack<<<dim3(8192), dim3(256), 0, stream>>>(E_topic, Etp_pk, 1024); // K=8192,N=1024
  cast_pack<<<dim3(8192), dim3(256), 0, stream>>>(gen_W, genW_pk, 8192);  // K=1024,N=8192
  src_build<<<dim3(64,280), dim3(256), 0, stream>>>(
      E_ctx, context, ctx_len, pvh, pv_mask, tp_hidden, tp_len, ar_hidden, ar_len, src_bf, smask);
  abuf_init<<<dim3(32,64), dim3(256), 0, stream>>>(Abuf);

  // ---- decode loop ----
  for (int t = 0; t < PREF_; ++t){
    hipMemsetAsync(emb, 0, zbytes, stream);
    // emb = y @ E_topic   (K=8192)
    bgemm<64,true,false><<<dim3(8,1,16), dim3(256), 0, stream>>>(
        Abuf, V_, Etp_pk, H_, emb, H_, 512, nullptr);
    embcast<<<dim3(64), dim3(256), 0, stream>>>(emb, EA);
    // qk = emb @ Mw   (K=1024)
    bgemm<64,true,false><<<dim3(8,1,2), dim3(256), 0, stream>>>(
        EA, 2048, Mw_pk, H_, qk, H_, 512, nullptr);
    // attention
    attn_pass<<<dim3(64,16), dim3(256), 0, stream>>>(qk, src_bf, smask, part_o, part_ml);
    attn_combine<<<dim3(64), dim3(256), 0, stream>>>(part_o, part_ml, EA);
    // decr = [emb|asrc] @ [Wo;Wvo]   (K=2048)
    bgemm<64,true,false><<<dim3(8,1,4), dim3(256), 0, stream>>>(
        EA, 2048, WoV_pk, H_, decr, H_, 512, nullptr);
    tanhcast<<<dim3(64), dim3(256), 0, stream>>>(decr, dtan);
    // gen = tanh(decr) @ gen_W + b  (K=1024, N=8192) — single-chunk, non-atomic
    bgemm<64,false,true><<<dim3(64,1,1), dim3(256), 0, stream>>>(
        dtan, H_, genW_pk, V_, gen, V_, 1024, gen_b);
    // copy logits
    copy_score<<<dim3(64,16), dim3(256), 0, stream>>>(dtan, src_bf, smask, cl);
    // softmax stats + p + scatter + sample (fused)
    fuse_out<<<dim3(64), dim3(1024), 0, stream>>>(
        gen, cl, pv_m, context, glo2loc, tp_path, out0, out1, Abuf, t);
  }
}

// Round 4
// 2216.678 us; speedup vs baseline: 1.5074x; 1.2271x over previous
//
#include <hip/hip_runtime.h>
#include <hip/hip_bf16.h>
#include <stdint.h>

#define B_    64
#define LC_   512
#define V_    8192
#define H_    1024
#define PREF_ 16
#define S_    545
#define SP_   560          // padded src rows (545 -> 560 = 35*16)
#define NEGV  (-1e9f)
#define INV32 0.03125f     // H^-0.5

typedef __attribute__((ext_vector_type(8))) short s8v;   // 8 bf16 MFMA frag
typedef __attribute__((ext_vector_type(4))) float f4a;   // MFMA C/D frag

__device__ __forceinline__ short f2bf(float f){
  uint32_t u = __float_as_uint(f);
  uint32_t r = (u + 0x7fffu + ((u >> 16) & 1u)) >> 16;
  return (short)(r & 0xffffu);
}
__device__ __forceinline__ float bf2f(short s){
  return __uint_as_float(((uint32_t)(uint16_t)s) << 16);
}

// ---------------- threefry2x32 (exact JAX semantics) ----------------
__device__ __forceinline__ uint32_t rotl32(uint32_t x, uint32_t d){ return (x<<d)|(x>>(32u-d)); }
__device__ __forceinline__ void tf2x32(uint32_t k0, uint32_t k1, uint32_t& x0, uint32_t& x1){
  uint32_t ks0=k0, ks1=k1, ks2=k0^k1^0x1BD11BDAu;
  x0+=ks0; x1+=ks1;
  x0+=x1; x1=rotl32(x1,13); x1^=x0;
  x0+=x1; x1=rotl32(x1,15); x1^=x0;
  x0+=x1; x1=rotl32(x1,26); x1^=x0;
  x0+=x1; x1=rotl32(x1, 6); x1^=x0;
  x0+=ks1; x1+=ks2+1u;
  x0+=x1; x1=rotl32(x1,17); x1^=x0;
  x0+=x1; x1=rotl32(x1,29); x1^=x0;
  x0+=x1; x1=rotl32(x1,16); x1^=x0;
  x0+=x1; x1=rotl32(x1,24); x1^=x0;
  x0+=ks2; x1+=ks0+2u;
  x0+=x1; x1=rotl32(x1,13); x1^=x0;
  x0+=x1; x1=rotl32(x1,15); x1^=x0;
  x0+=x1; x1=rotl32(x1,26); x1^=x0;
  x0+=x1; x1=rotl32(x1, 6); x1^=x0;
  x0+=ks0; x1+=ks1+3u;
  x0+=x1; x1=rotl32(x1,17); x1^=x0;
  x0+=x1; x1=rotl32(x1,29); x1^=x0;
  x0+=x1; x1=rotl32(x1,16); x1^=x0;
  x0+=x1; x1=rotl32(x1,24); x1^=x0;
  x0+=ks1; x1+=ks2+4u;
  x0+=x1; x1=rotl32(x1,13); x1^=x0;
  x0+=x1; x1=rotl32(x1,15); x1^=x0;
  x0+=x1; x1=rotl32(x1,26); x1^=x0;
  x0+=x1; x1=rotl32(x1, 6); x1^=x0;
  x0+=ks2; x1+=ks0+5u;
}

// ---------------- casts ----------------
__global__ __launch_bounds__(256) void cast_bf(const float* __restrict__ in, short* __restrict__ out){
  size_t idx = ((size_t)blockIdx.x*256 + threadIdx.x)*4;
  float4 v = *(const float4*)(in+idx);
  short4 s; s.x=f2bf(v.x); s.y=f2bf(v.y); s.z=f2bf(v.z); s.w=f2bf(v.w);
  *(short4*)(out+idx) = s;
}
// fp32 [K][N] -> k-packeted bf16: off(k,n) = ((k>>3)*N + n)*8 + (k&7)
__global__ __launch_bounds__(256) void cast_pack(const float* __restrict__ in, short* __restrict__ out, int N){
  int gid = blockIdx.x*256 + threadIdx.x;
  int k = gid / (N>>2);
  int n = (gid % (N>>2))*4;
  float4 v = *(const float4*)(in + (size_t)k*N + n);
  size_t base = ((size_t)(k>>3)*N + n)*8 + (k&7);
  out[base] = f2bf(v.x); out[base+8] = f2bf(v.y); out[base+16] = f2bf(v.z); out[base+24] = f2bf(v.w);
}
// fp32 [N][K] row-major -> packed transpose: B(k,n) = in[n][k], k-packeted
__global__ __launch_bounds__(256) void cast_packT(const float* __restrict__ in, short* __restrict__ out, int N, int K){
  int gid = blockIdx.x*256 + threadIdx.x;
  int n = gid / (K>>2);
  int k = (gid % (K>>2))*4;
  float4 v = *(const float4*)(in + (size_t)n*K + k);
  size_t base = ((size_t)(k>>3)*N + n)*8 + (k&7);
  short4 s4; s4.x=f2bf(v.x); s4.y=f2bf(v.y); s4.z=f2bf(v.z); s4.w=f2bf(v.w);
  *(short4*)(out + base) = s4;     // (k&7) in {0,4} -> 8B aligned
}
// emb fp32 [64][1024] -> EA bf16 row-major lda 2048, cols 0..1023
__global__ __launch_bounds__(256) void embcast(const float* __restrict__ emb, short* __restrict__ EA){
  int idx = blockIdx.x*256 + threadIdx.x;     // grid 64 -> 16384 float4
  int row = idx >> 8, c4 = idx & 255;
  float4 v = ((const float4*)(emb + (size_t)row*1024))[c4];
  short4 s; s.x=f2bf(v.x); s.y=f2bf(v.y); s.z=f2bf(v.z); s.w=f2bf(v.w);
  *(short4*)(EA + (size_t)row*2048 + c4*4) = s;
}

// ---------------- bf16-in GEMM: A row-major bf16 (direct-global frags), B k-packeted bf16 ----------------
// double-buffered B staging: stage tile k+1 while computing tile k (one barrier/iter)
template<int BM, bool ATOMIC, bool BIAS>
__global__ __launch_bounds__(256) void bgemm(
    const short* __restrict__ A, int lda,
    const short* __restrict__ Bp, int ldn,
    float* __restrict__ C, int ldc,
    int kchunk, const float* __restrict__ bias)
{
  constexpr int BN = 128, BK = 64;
  __shared__ short Bl[2][BK*BN];
  const int t = threadIdx.x;
  const int w = t >> 6, lane = t & 63;
  const int quad = lane >> 4, l16 = lane & 15;
  const int col0 = blockIdx.x * BN;
  const int row0 = (BM==128) ? blockIdx.y * BM : 0;
  const int k0 = blockIdx.z * kchunk;
  const int nk = kchunk / BK;
  constexpr int MT = 2;
  constexpr int NT = (BM==128) ? 8 : 4;
  const int mbase = (BM==128) ? w*32 : (w&1)*32;
  const int nbase = (BM==128) ? 0 : (w>>1)*64;
  f4a acc[MT][NT];
  #pragma unroll
  for (int mt=0; mt<MT; mt++)
    #pragma unroll
    for (int nt=0; nt<NT; nt++)
      acc[mt][nt] = (f4a){0.f,0.f,0.f,0.f};

  auto stage = [&](int kb, int buf){
    #pragma unroll
    for (int i=0;i<4;i++){                      // stage B tile: 1024 short8
      int idx = t + i*256;
      int p = idx >> 7, n = idx & 127;
      ((s8v*)Bl[buf])[idx] = *(const s8v*)(Bp + (((size_t)((kb>>3)+p))*ldn + col0 + n)*8);
    }
  };

  stage(k0, 0);
  __syncthreads();
  for (int it=0; it<nk; ++it){
    const int kb = k0 + it*BK;
    const int cur = it & 1;
    if (it+1 < nk) stage(kb + BK, cur^1);
    #pragma unroll
    for (int ks=0; ks<BK; ks+=32){
      const int kk = kb + ks + quad*8;
      const int kl = ks + quad*8;
      s8v af[MT], bfr[NT];
      #pragma unroll
      for (int mt=0; mt<MT; mt++)
        af[mt] = *(const s8v*)(A + (size_t)(row0+mbase+mt*16+l16)*lda + kk);
      #pragma unroll
      for (int nt=0; nt<NT; nt++)
        bfr[nt] = *(const s8v*)&Bl[cur][((kl>>3)*BN + nbase + nt*16 + l16)*8];
      #pragma unroll
      for (int mt=0; mt<MT; mt++)
        #pragma unroll
        for (int nt=0; nt<NT; nt++)
          acc[mt][nt] = __builtin_amdgcn_mfma_f32_16x16x32_bf16(af[mt], bfr[nt], acc[mt][nt], 0, 0, 0);
    }
    __syncthreads();
  }
  #pragma unroll
  for (int mt=0; mt<MT; mt++){
    #pragma unroll
    for (int nt=0; nt<NT; nt++){
      #pragma unroll
      for (int r=0; r<4; r++){
        int row = row0 + mbase + mt*16 + quad*4 + r;
        int cc  = col0 + nbase + nt*16 + l16;
        float v = acc[mt][nt][r];
        if (BIAS){ if (!ATOMIC || blockIdx.z==0) v += bias[cc]; }
        size_t idx = (size_t)row*ldc + cc;
        if (ATOMIC) atomicAdd(&C[idx], v);
        else        C[idx] = v;
      }
    }
  }
}

// ---------------- src_hidden materialization (bf16) + mask ----------------
__global__ __launch_bounds__(256) void src_build(
    const float* __restrict__ E_ctx, const int* __restrict__ context, const int* __restrict__ ctx_len,
    const float* __restrict__ pvh, const float* __restrict__ pv_mask,
    const float* __restrict__ tp_hidden, const int* __restrict__ tp_len,
    const float* __restrict__ ar_hidden, const int* __restrict__ ar_len,
    short* __restrict__ src, float* __restrict__ smask)
{
  const int b = blockIdx.x, t = threadIdx.x;
  const int j = blockIdx.y*2 + (t >> 7);        // grid.y = 280 -> j in 0..559
  const int c = (t & 127) * 8;
  const float* srcp = nullptr;
  float msk = 0.f;
  if (j < 512){
    bool on = j < ctx_len[b];
    msk = on ? 1.f : 0.f;
    if (on) srcp = E_ctx + (size_t)context[b*LC_ + j]*H_;
  } else if (j < 528){
    srcp = pvh + (size_t)(b*16 + j-512)*H_;
    msk = pv_mask[b*16 + j-512];
  } else if (j < 544){
    srcp = tp_hidden + (size_t)(b*16 + j-528)*H_;
    msk = ((j-528) < tp_len[b]) ? 1.f : 0.f;
  } else if (j == 544){
    srcp = ar_hidden + (size_t)b*H_;
    msk = (ar_len[b] > 0) ? 1.f : 0.f;
  }
  if (srcp){
    float4 v0 = *(const float4*)(srcp + c);
    float4 v1 = *(const float4*)(srcp + c + 4);
    s8v s;
    s[0]=f2bf(v0.x); s[1]=f2bf(v0.y); s[2]=f2bf(v0.z); s[3]=f2bf(v0.w);
    s[4]=f2bf(v1.x); s[5]=f2bf(v1.y); s[6]=f2bf(v1.z); s[7]=f2bf(v1.w);
    *(s8v*)(src + (size_t)(b*SP_ + j)*H_ + c) = s;
  }
  if ((t & 127) == 0) smask[b*SP_ + j] = msk;
}

__global__ __launch_bounds__(256) void abuf_init(short* __restrict__ Abuf){
  int v = blockIdx.x*256 + threadIdx.x;  // grid (32, 64) -> v in 0..8191
  int b = blockIdx.y;
  Abuf[(size_t)b*V_ + v] = (v == 2) ? (short)0x3F80 : (short)0;
}

// ---------------- attention: flash chunk pass over bf16 src (16 chunks x 35 rows) ----------------
__global__ __launch_bounds__(256) void attn_pass(
    const float* __restrict__ qk, const short* __restrict__ src, const float* __restrict__ smask,
    float* __restrict__ part_o, float* __restrict__ part_ml)
{
  const int b = blockIdx.x, c = blockIdx.y, t = threadIdx.x;
  const int w = t>>6, lane = t&63;
  __shared__ float sv[35], pr[35], red[4];
  float qreg[16];
  {
    const float4* q4 = (const float4*)(qk + (size_t)b*H_ + lane*16);
    #pragma unroll
    for (int i=0;i<4;i++){ float4 v = q4[i]; qreg[4*i]=v.x; qreg[4*i+1]=v.y; qreg[4*i+2]=v.z; qreg[4*i+3]=v.w; }
  }
  const int j0 = c*35;
  for (int r = w; r < 35; r += 4){
    float msk = smask[b*SP_ + j0 + r];
    float s = -3.4e38f;
    if (msk != 0.f){
      const s8v* rp = (const s8v*)(src + (size_t)(b*SP_ + j0 + r)*H_);
      s8v v0 = rp[lane*2], v1 = rp[lane*2+1];
      float acc = 0.f;
      #pragma unroll
      for (int i=0;i<8;i++) acc += bf2f(v0[i])*qreg[i];
      #pragma unroll
      for (int i=0;i<8;i++) acc += bf2f(v1[i])*qreg[8+i];
      #pragma unroll
      for (int off=32; off; off>>=1) acc += __shfl_down(acc, off, 64);
      s = acc * INV32;
    }
    if (lane == 0) sv[r] = s;
  }
  __syncthreads();
  float lm = (t < 35) ? sv[t] : -3.4e38f;
  #pragma unroll
  for (int off=32; off; off>>=1) lm = fmaxf(lm, __shfl_down(lm, off, 64));
  if (lane==0) red[w] = lm;
  __syncthreads();
  const float m = fmaxf(fmaxf(red[0],red[1]), fmaxf(red[2],red[3]));
  __syncthreads();
  if (t < 35) pr[t] = (sv[t] > -1e37f) ? expf(sv[t]-m) : 0.f;
  __syncthreads();
  float ls = (t < 35) ? pr[t] : 0.f;
  #pragma unroll
  for (int off=32; off; off>>=1) ls += __shfl_down(ls, off, 64);
  if (lane==0) red[w] = ls;
  __syncthreads();
  const float lsum = red[0]+red[1]+red[2]+red[3];
  float4 o = {0.f,0.f,0.f,0.f};
  const short* base = src + (size_t)(b*SP_ + j0)*H_ + t*4;
  for (int r=0;r<35;r++){
    float p_ = pr[r];
    if (p_ != 0.f){
      short4 s4 = *(const short4*)(base + (size_t)r*H_);
      o.x += p_*bf2f(s4.x); o.y += p_*bf2f(s4.y); o.z += p_*bf2f(s4.z); o.w += p_*bf2f(s4.w);
    }
  }
  ((float4*)(part_o + (size_t)(b*16+c)*H_))[t] = o;
  if (t==0){ part_ml[(b*16+c)*2] = m; part_ml[(b*16+c)*2+1] = lsum; }
}

// combine 16 chunks -> asrc, written as bf16 into EA cols [1024..2047]
__global__ __launch_bounds__(256) void attn_combine(
    const float* __restrict__ part_o, const float* __restrict__ part_ml,
    short* __restrict__ EA)
{
  const int b = blockIdx.x, t = threadIdx.x;
  __shared__ float sm[16], sl[16];
  if (t < 16){ sm[t] = part_ml[(b*16+t)*2]; sl[t] = part_ml[(b*16+t)*2+1]; }
  __syncthreads();
  float M = -3.4e38f;
  #pragma unroll
  for (int i=0;i<16;i++) M = fmaxf(M, sm[i]);
  float wgt[16]; float Z = 0.f;
  #pragma unroll
  for (int i=0;i<16;i++){ wgt[i] = expf(sm[i]-M); Z += wgt[i]*sl[i]; }
  float4 o = {0.f,0.f,0.f,0.f};
  #pragma unroll
  for (int i=0;i<16;i++){
    float4 p = ((const float4*)(part_o + (size_t)(b*16+i)*H_))[t];
    o.x += wgt[i]*p.x; o.y += wgt[i]*p.y; o.z += wgt[i]*p.z; o.w += wgt[i]*p.w;
  }
  float inv = 1.f / Z;
  short4 s4; s4.x=f2bf(o.x*inv); s4.y=f2bf(o.y*inv); s4.z=f2bf(o.z*inv); s4.w=f2bf(o.w*inv);
  *(short4*)(EA + (size_t)b*2048 + 1024 + t*4) = s4;
}

// dtan = bf16(tanh(decr))
__global__ __launch_bounds__(256) void tanhcast(const float* __restrict__ decr, short* __restrict__ dtan){
  int idx = blockIdx.x*256 + threadIdx.x;   // grid 64 -> 16384 float4
  float4 v = ((const float4*)decr)[idx];
  short4 s; s.x=f2bf(tanhf(v.x)); s.y=f2bf(tanhf(v.y)); s.z=f2bf(tanhf(v.z)); s.w=f2bf(tanhf(v.w));
  ((short4*)dtan)[idx] = s;
}

// ---------------- copy logits over bf16 src (16 chunks x 34 rows) ----------------
__global__ __launch_bounds__(256) void copy_score(
    const short* __restrict__ dtan, const short* __restrict__ src, const float* __restrict__ smask,
    float* __restrict__ cl)
{
  const int b = blockIdx.x, c = blockIdx.y, t = threadIdx.x;
  const int w = t>>6, lane = t&63;
  float qd[16];
  {
    const s8v* d8 = (const s8v*)(dtan + (size_t)b*H_ + lane*16);
    s8v d0 = d8[0], d1 = d8[1];
    #pragma unroll
    for (int i=0;i<8;i++){ qd[i] = bf2f(d0[i]); qd[8+i] = bf2f(d1[i]); }
  }
  for (int r = w; r < 34; r += 4){
    int j = c*34 + r;
    float msk = smask[b*SP_ + j];
    float s;
    if (msk != 0.f){
      const s8v* rp = (const s8v*)(src + (size_t)(b*SP_ + j)*H_);
      s8v v0 = rp[lane*2], v1 = rp[lane*2+1];
      float acc = 0.f;
      #pragma unroll
      for (int i=0;i<8;i++) acc += bf2f(v0[i])*qd[i];
      #pragma unroll
      for (int i=0;i<8;i++) acc += bf2f(v1[i])*qd[8+i];
      #pragma unroll
      for (int off=32; off; off>>=1) acc += __shfl_down(acc, off, 64);
      s = acc * INV32;
    } else s = NEGV * INV32;
    if (lane == 0) cl[b*544 + j] = s;
  }
}

// ---------------- fused: softmax stats + p build + scatter + gumbel sample ----------------
// each thread owns 8 consecutive vocab elements [8t, 8t+8); pv_m read as bf16
__global__ __launch_bounds__(1024) void fuse_out(
    const float* __restrict__ gen, const float* __restrict__ cl, const short* __restrict__ pvm,
    const int* __restrict__ context, const int* __restrict__ glo2loc, const int* __restrict__ tp_path,
    float* __restrict__ out0, float* __restrict__ out1, short* __restrict__ Abuf, int step)
{
  const int b = blockIdx.x, t = threadIdx.x;
  const int w = t>>6, lane = t&63;
  __shared__ float pl[V_];
  __shared__ float red[16];
  __shared__ float pvp[16];
  float ge[8];
  const float4* g4 = (const float4*)(gen + (size_t)b*V_);
  float lm = -3.4e38f;
  {
    float4 ga = g4[2*t], gb = g4[2*t+1];
    ge[0]=ga.x*INV32; ge[1]=ga.y*INV32; ge[2]=ga.z*INV32; ge[3]=ga.w*INV32;
    ge[4]=gb.x*INV32; ge[5]=gb.y*INV32; ge[6]=gb.z*INV32; ge[7]=gb.w*INV32;
    #pragma unroll
    for (int k=0;k<8;k++) lm = fmaxf(lm, ge[k]);
  }
  if (t < 544) lm = fmaxf(lm, cl[b*544+t]);
  #pragma unroll
  for (int off=32; off; off>>=1) lm = fmaxf(lm, __shfl_down(lm, off, 64));
  if (lane==0) red[w] = lm;
  __syncthreads();
  float m = red[0];
  #pragma unroll
  for (int i=1;i<16;i++) m = fmaxf(m, red[i]);
  __syncthreads();
  float ls = 0.f;
  #pragma unroll
  for (int k=0;k<8;k++){ ge[k] = expf(ge[k] - m); ls += ge[k]; }
  if (t < 544) ls += expf(cl[b*544+t] - m);
  #pragma unroll
  for (int off=32; off; off>>=1) ls += __shfl_down(ls, off, 64);
  if (lane==0) red[w] = ls;
  __syncthreads();
  float Z = red[0];
  #pragma unroll
  for (int i=1;i<16;i++) Z += red[i];
  const float invZ = 1.f / Z;
  if (t < 16) pvp[t] = expf(cl[b*544 + 512 + t] - m) * invZ;
  __syncthreads();
  #pragma unroll
  for (int k=0;k<8;k++) ge[k] *= invZ;
  const short* pvb = pvm + (size_t)b*16*V_ + 8*t;
  #pragma unroll 4
  for (int l=0;l<16;l++){
    float wl = pvp[l];
    s8v q = *(const s8v*)(pvb + (size_t)l*V_);
    #pragma unroll
    for (int k=0;k<8;k++) ge[k] += wl*bf2f(q[k]);
  }
  {
    float4 pa = {ge[0],ge[1],ge[2],ge[3]}, pb = {ge[4],ge[5],ge[6],ge[7]};
    ((float4*)pl)[2*t] = pa; ((float4*)pl)[2*t+1] = pb;
  }
  __syncthreads();
  if (t < 528){
    float val; int tgt;
    if (t < 512){
      val = expf(cl[b*544 + t] - m) * invZ;
      tgt = glo2loc[context[b*LC_ + t]];
    } else {
      int l = t - 512;
      val = expf(cl[b*544 + 528 + l] - m) * invZ;
      tgt = tp_path[b*16 + l];
    }
    if (val != 0.f) atomicAdd(&pl[tgt], val);
  }
  __syncthreads();
  // out0 + gumbel sample
  float* o0 = out0 + (size_t)(b*PREF_+step)*V_;
  uint32_t kx = 0u, ky = (uint32_t)step;
  tf2x32(0u, 42u, kx, ky);
  float lv[8];
  float lm2 = -3.4e38f;
  {
    float4 pa = ((const float4*)pl)[2*t], pb = ((const float4*)pl)[2*t+1];
    ((float4*)o0)[2*t] = pa; ((float4*)o0)[2*t+1] = pb;
    float pe[8] = {pa.x,pa.y,pa.z,pa.w, pb.x,pb.y,pb.z,pb.w};
    #pragma unroll
    for (int k=0;k<8;k++){
      int v = 8*t + k;
      uint32_t j = (uint32_t)(b*V_ + v);
      uint32_t x0 = 0u, x1 = j;
      tf2x32(kx, ky, x0, x1);
      uint32_t bits = x0 ^ x1;
      float f = __uint_as_float((bits >> 9) | 0x3F800000u) - 1.0f;
      float u = fmaxf(1e-10f, f + 1e-10f);
      float g = -logf(-logf(u));
      float l = (logf(pe[k] + 1e-10f) + g) / 0.67f;
      lv[k] = l;
      lm2 = fmaxf(lm2, l);
    }
  }
  #pragma unroll
  for (int off=32; off; off>>=1) lm2 = fmaxf(lm2, __shfl_down(lm2, off, 64));
  if (lane==0) red[w] = lm2;
  __syncthreads();
  float m2 = red[0];
  #pragma unroll
  for (int i=1;i<16;i++) m2 = fmaxf(m2, red[i]);
  __syncthreads();
  float ls2 = 0.f;
  #pragma unroll
  for (int k=0;k<8;k++){ lv[k] = expf(lv[k] - m2); ls2 += lv[k]; }
  #pragma unroll
  for (int off=32; off; off>>=1) ls2 += __shfl_down(ls2, off, 64);
  if (lane==0) red[w] = ls2;
  __syncthreads();
  float Z2 = red[0];
  #pragma unroll
  for (int i=1;i<16;i++) Z2 += red[i];
  float* y = out1 + (size_t)(b*PREF_ + step)*V_;
  short* ab = Abuf + (size_t)b*V_;
  {
    float4 y4a; y4a.x = lv[0]/Z2; y4a.y = lv[1]/Z2; y4a.z = lv[2]/Z2; y4a.w = lv[3]/Z2;
    float4 y4b; y4b.x = lv[4]/Z2; y4b.y = lv[5]/Z2; y4b.z = lv[6]/Z2; y4b.w = lv[7]/Z2;
    ((float4*)y)[2*t] = y4a; ((float4*)y)[2*t+1] = y4b;
    s8v s;
    s[0]=f2bf(y4a.x); s[1]=f2bf(y4a.y); s[2]=f2bf(y4a.z); s[3]=f2bf(y4a.w);
    s[4]=f2bf(y4b.x); s[5]=f2bf(y4b.y); s[6]=f2bf(y4b.z); s[7]=f2bf(y4b.w);
    *(s8v*)(ab + 8*t) = s;
  }
}

// ---------------- host ----------------
extern "C" void kernel_launch(void* const* d_in, const int* in_sizes, int n_in,
                              void* d_out, int out_size, void* d_ws, size_t ws_size,
                              hipStream_t stream)
{
  (void)in_sizes; (void)n_in; (void)out_size; (void)ws_size;
  const int*   context   = (const int*)  d_in[0];
  const int*   ctx_len   = (const int*)  d_in[1];
  const float* pv_m      = (const float*)d_in[2];
  const float* pv_mask   = (const float*)d_in[3];
  const int*   ar_len    = (const int*)  d_in[5];
  const int*   tp_path   = (const int*)  d_in[6];
  const int*   tp_len    = (const int*)  d_in[7];
  const float* tp_hidden = (const float*)d_in[8];
  const float* ar_hidden = (const float*)d_in[9];
  const float* E_ctx     = (const float*)d_in[10];
  const float* W_p       = (const float*)d_in[11];
  const float* E_topic   = (const float*)d_in[12];
  const float* W_q       = (const float*)d_in[13];
  const float* W_k       = (const float*)d_in[14];
  const float* W_v       = (const float*)d_in[15];
  const float* W_o       = (const float*)d_in[16];
  const float* gen_W     = (const float*)d_in[17];
  const float* gen_b     = (const float*)d_in[18];
  const int*   glo2loc   = (const int*)  d_in[19];

  float* out0 = (float*)d_out;
  float* out1 = out0 + (size_t)B_*PREF_*V_;

  // ---- workspace layout ----
  short* sw      = (short*)d_ws;
  short* Etp_pk  = sw;  sw += (size_t)8192*1024;     // E_topic, k-packeted (K=8192,N=1024)
  short* genW_pk = sw;  sw += (size_t)1024*8192;     // gen_W packed (K=1024,N=8192)
  short* WoV_pk  = sw;  sw += (size_t)2048*1024;     // [W_o ; W_v@W_o] packed (K=2048,N=1024)
  short* Mw_pk   = sw;  sw += (size_t)1024*1024;     // Wq@Wk^T packed (K=1024,N=1024)
  short* pvm_bf  = sw;  sw += (size_t)1024*8192;     // pv_m bf16 (persistent; fuse_out reads it)
  short* Abuf    = sw;  sw += (size_t)B_*V_;         // y bf16 (64x8192)
  short* EA      = sw;  sw += (size_t)B_*2048;       // [emb | asrc] bf16 (64x2048)
  short* dtan    = sw;  sw += (size_t)B_*H_;
  short* src_bf  = sw;  sw += (size_t)B_*SP_*H_;     // materialized src_hidden bf16
  // setup-only aliases inside src_bf (consumed before src_build writes it)
  short* Wp_pk   = src_bf;                            // 8192*1024
  short* wq_bf   = src_bf + (size_t)8192*1024;        // 1024*1024
  short* wv_bf   = wq_bf  + (size_t)1024*1024;
  short* WkT_pk  = wv_bf  + (size_t)1024*1024;
  float* fw      = (float*)sw;
  float* smask   = fw;  fw += B_*SP_;
  float* pvh     = fw;  fw += 1024*1024;
  float* emb     = fw;  fw += B_*H_;                 // -- zero region start --
  float* qk      = fw;  fw += B_*H_;
  float* decr    = fw;  fw += B_*H_;                 // -- zero region end --
  float* gen     = fw;  fw += (size_t)B_*V_;         // non-atomic, no memset needed
  float* part_o  = fw;  fw += (size_t)B_*16*H_;
  float* part_ml = fw;  fw += B_*16*2;
  float* cl      = fw;  fw += B_*544;
  const size_t zbytes = (size_t)(3*B_*H_) * sizeof(float);
  // setup-only fp32 scratch (aliased over buffers whose real use comes later)
  float* Mw_f  = pvh;     // packed before pvh's real (pv_hidden) use
  float* Wvo_f = part_o;  // overwritten by attn_pass each step

  // ---- one-time setup ----
  // small 1024^3 GEMMs via bgemm (K-split z=4, fp32 atomic out, then pack)
  hipMemsetAsync(Mw_f,  0, (size_t)1024*1024*sizeof(float), stream);
  hipMemsetAsync(Wvo_f, 0, (size_t)1024*1024*sizeof(float), stream);
  cast_bf   <<<dim3(1024), dim3(256), 0, stream>>>(W_q, wq_bf);
  cast_packT<<<dim3(1024), dim3(256), 0, stream>>>(W_k, WkT_pk, 1024, 1024);
  cast_bf   <<<dim3(1024), dim3(256), 0, stream>>>(W_v, wv_bf);
  cast_pack <<<dim3(1024), dim3(256), 0, stream>>>(W_o, WoV_pk, 1024);     // Wo -> rows 0..1023
  bgemm<128,true,false><<<dim3(8,8,4), dim3(256), 0, stream>>>(
      wq_bf, 1024, WkT_pk, 1024, Mw_f, 1024, 256, nullptr);                // Mw = Wq@Wk^T
  cast_pack <<<dim3(1024), dim3(256), 0, stream>>>(Mw_f, Mw_pk, 1024);
  bgemm<128,true,false><<<dim3(8,8,4), dim3(256), 0, stream>>>(
      wv_bf, 1024, WoV_pk, 1024, Wvo_f, 1024, 256, nullptr);               // Wvo = Wv@Wo
  cast_pack <<<dim3(1024), dim3(256), 0, stream>>>(Wvo_f, WoV_pk + (size_t)1024*1024, 1024);
  // pv_hidden (pvh reused: memset after Mw_f lifetime ends)
  hipMemsetAsync(pvh, 0, (size_t)1024*1024*sizeof(float), stream);
  cast_bf  <<<dim3(8192), dim3(256), 0, stream>>>(pv_m, pvm_bf);           // 1024x8192
  cast_pack<<<dim3(8192), dim3(256), 0, stream>>>(W_p, Wp_pk, 1024);       // K=8192,N=1024
  bgemm<128,true,false><<<dim3(8,8,4), dim3(256), 0, stream>>>(
      pvm_bf, 8192, Wp_pk, 1024, pvh, 1024, 2048, nullptr);                // pv_hidden
  cast_pack<<<dim3(8192), dim3(256), 0, stream>>>(E_topic, Etp_pk, 1024);  // K=8192,N=1024
  cast_pack<<<dim3(8192), dim3(256), 0, stream>>>(gen_W, genW_pk, 8192);   // K=1024,N=8192
  src_build<<<dim3(64,280), dim3(256), 0, stream>>>(
      E_ctx, context, ctx_len, pvh, pv_mask, tp_hidden, tp_len, ar_hidden, ar_len, src_bf, smask);
  abuf_init<<<dim3(32,64), dim3(256), 0, stream>>>(Abuf);

  // ---- decode loop ----
  for (int t = 0; t < PREF_; ++t){
    hipMemsetAsync(emb, 0, zbytes, stream);
    // emb = y @ E_topic   (K=8192)
    bgemm<64,true,false><<<dim3(8,1,16), dim3(256), 0, stream>>>(
        Abuf, V_, Etp_pk, H_, emb, H_, 512, nullptr);
    embcast<<<dim3(64), dim3(256), 0, stream>>>(emb, EA);
    // qk = emb @ Mw   (K=1024, z=8 -> 64 blocks)
    bgemm<64,true,false><<<dim3(8,1,8), dim3(256), 0, stream>>>(
        EA, 2048, Mw_pk, H_, qk, H_, 128, nullptr);
    // attention
    attn_pass<<<dim3(64,16), dim3(256), 0, stream>>>(qk, src_bf, smask, part_o, part_ml);
    attn_combine<<<dim3(64), dim3(256), 0, stream>>>(part_o, part_ml, EA);
    // decr = [emb|asrc] @ [Wo;Wvo]   (K=2048, z=8 -> 64 blocks)
    bgemm<64,true,false><<<dim3(8,1,8), dim3(256), 0, stream>>>(
        EA, 2048, WoV_pk, H_, decr, H_, 256, nullptr);
    tanhcast<<<dim3(64), dim3(256), 0, stream>>>(decr, dtan);
    // gen = tanh(decr) @ gen_W + b  (K=1024, N=8192) — single-chunk, non-atomic
    bgemm<64,false,true><<<dim3(64,1,1), dim3(256), 0, stream>>>(
        dtan, H_, genW_pk, V_, gen, V_, 1024, gen_b);
    // copy logits
    copy_score<<<dim3(64,16), dim3(256), 0, stream>>>(dtan, src_bf, smask, cl);
    // softmax stats + p + scatter + sample (fused)
    fuse_out<<<dim3(64), dim3(1024), 0, stream>>>(
        gen, cl, pvm_bf, context, glo2loc, tp_path, out0, out1, Abuf, t);
  }
}